// Round 1
// baseline (60656.519 us; speedup 1.0000x reference)
//
#include <hip/hip_runtime.h>
#include <hip/hip_cooperative_groups.h>

namespace cg = cooperative_groups;

typedef unsigned short u16;
typedef unsigned int u32;
typedef __attribute__((ext_vector_type(8))) short bf16x8;   // 8 bf16 in 4 VGPRs
typedef __attribute__((ext_vector_type(4))) float f32x4;

#define T_ 512
#define B_ 64
#define IN_ 128
#define H_ 512
#define C_ 32
#define BH_ (B_ * H_)        // 32768 elems per h plane
#define NWG_CELL 128
#define NWG_TOT 132

// ---------- bf16 split helpers (RNE) ----------
__device__ inline u16 f2bf_(float f) {
    u32 u = __float_as_uint(f);
    u32 r = (u + 0x7FFFu + ((u >> 16) & 1u)) >> 16;
    return (u16)r;
}
__device__ inline float bf2f_(u16 h) { return __uint_as_float(((u32)h) << 16); }

// ---------- weight / h0 split kernel: fp32 -> (hi, lo) bf16 planes ----------
__global__ void split_kernel(const float* __restrict__ src, u16* __restrict__ hi,
                             u16* __restrict__ lo, int n) {
    int i = blockIdx.x * 256 + threadIdx.x;
    if (i < n) {
        float f = src[i];
        u16 h = f2bf_(f);
        hi[i] = h;
        lo[i] = f2bf_(f - bf2f_(h));
    }
}

// ---------- params ----------
struct Params {
    const float* x;
    const u16* ih_hi[3]; const u16* ih_lo[3];
    const u16* hh_hi[3]; const u16* hh_lo[3];
    const float* b_ih[3]; const float* b_hh[3];
    const u16* wout_hi; const u16* wout_lo;
    const float* b_out;
    u16* h_hi; u16* h_lo;   // [3 layers][2 slots][B*H]
    float* y;               // [B][T][C]
};

// ---------- MFMA helpers ----------
__device__ inline bf16x8 ld8(const u16* p) { return *reinterpret_cast<const bf16x8*>(p); }

__device__ inline f32x4 mfma3(bf16x8 ah, bf16x8 al, bf16x8 bh, bf16x8 bl, f32x4 c) {
    c = __builtin_amdgcn_mfma_f32_16x16x32_bf16(ah, bh, c, 0, 0, 0);
    c = __builtin_amdgcn_mfma_f32_16x16x32_bf16(al, bh, c, 0, 0, 0);
    c = __builtin_amdgcn_mfma_f32_16x16x32_bf16(ah, bl, c, 0, 0, 0);
    return c;
}

template <int NKT>
__device__ inline f32x4 gemm_tile(const u16* Ah, const u16* Al,
                                  const u16* Bh, const u16* Bl, int lhi) {
    f32x4 acc = {0.f, 0.f, 0.f, 0.f};
#pragma unroll
    for (int kt = 0; kt < NKT; ++kt) {
        const int kb = kt * 32 + lhi * 8;
        acc = mfma3(ld8(Ah + kb), ld8(Al + kb), ld8(Bh + kb), ld8(Bl + kb), acc);
    }
    return acc;
}

template <int NKT>
__device__ inline void gemm_tile2(const u16* Ah, const u16* Al,
                                  const u16* B0h, const u16* B0l,
                                  const u16* B1h, const u16* B1l,
                                  int lhi, f32x4& o0, f32x4& o1) {
    f32x4 a0 = {0.f, 0.f, 0.f, 0.f}, a1 = {0.f, 0.f, 0.f, 0.f};
#pragma unroll
    for (int kt = 0; kt < NKT; ++kt) {
        const int kb = kt * 32 + lhi * 8;
        bf16x8 ah = ld8(Ah + kb), al = ld8(Al + kb);
        a0 = mfma3(ah, al, ld8(B0h + kb), ld8(B0l + kb), a0);
        a1 = mfma3(ah, al, ld8(B1h + kb), ld8(B1l + kb), a1);
    }
    o0 = a0; o1 = a1;
}

// C/D layout (m89-verified): col = lane&15, row = (lane>>4)*4 + reg
__device__ inline void store_sg(float (&dst)[16][17], f32x4 a, int ln15, int lhi) {
#pragma unroll
    for (int q = 0; q < 4; ++q) dst[lhi * 4 + q][ln15] = a[q];
}

// ---------- one GRU cell phase for one WG ----------
// gates order (r,z,n); sg[0..2]=gi_{r,z,n}, sg[3..5]=gh_{r,z,n}
template <int L>
__device__ void cell_phase(const Params& p, int t, int rs, int wsl, int wg, int tid,
                           float (*sg)[16][17]) {
    const int wave = tid >> 6, lane = tid & 63;
    const int ln15 = lane & 15, lhi = lane >> 4;
    const int ug = wg & 31, mb = wg >> 5;      // stride-32 ids share XCD -> weight L2 reuse
    const int u0 = ug * 16, b0 = mb * 16;
    const size_t arow = (size_t)(b0 + ln15) * H_;

    const u16* hp_hi = p.h_hi + (size_t)(2 * L + rs) * BH_;   // h_own(t-1)
    const u16* hp_lo = p.h_lo + (size_t)(2 * L + rs) * BH_;

    if (L == 0) {
        if (wave < 3) {
            // gh gate = wave, A = h1(t-1), W_hh1, K=512
            const size_t brow = (size_t)(wave * H_ + u0 + ln15) * H_;
            f32x4 a = gemm_tile<16>(hp_hi + arow, hp_lo + arow,
                                    p.hh_hi[0] + brow, p.hh_lo[0] + brow, lhi);
            store_sg(sg[3 + wave], a, ln15, lhi);
        } else {
            // gi gates r,z,n from x_t (fp32 -> split on the fly), K=128
            const float* xr = p.x + (size_t)(b0 + ln15) * (T_ * IN_) + (size_t)t * IN_;
            const size_t br0 = (size_t)(0 * H_ + u0 + ln15) * IN_;
            const size_t br1 = (size_t)(1 * H_ + u0 + ln15) * IN_;
            const size_t br2 = (size_t)(2 * H_ + u0 + ln15) * IN_;
            f32x4 a0 = {0.f,0.f,0.f,0.f}, a1 = {0.f,0.f,0.f,0.f}, a2 = {0.f,0.f,0.f,0.f};
#pragma unroll
            for (int kt = 0; kt < 4; ++kt) {
                const int kb = kt * 32 + lhi * 8;
                bf16x8 ah, al;
#pragma unroll
                for (int j = 0; j < 8; ++j) {
                    float f = xr[kb + j];
                    u16 hb = f2bf_(f);
                    ah[j] = (short)hb;
                    al[j] = (short)f2bf_(f - bf2f_(hb));
                }
                a0 = mfma3(ah, al, ld8(p.ih_hi[0] + br0 + kb), ld8(p.ih_lo[0] + br0 + kb), a0);
                a1 = mfma3(ah, al, ld8(p.ih_hi[0] + br1 + kb), ld8(p.ih_lo[0] + br1 + kb), a1);
                a2 = mfma3(ah, al, ld8(p.ih_hi[0] + br2 + kb), ld8(p.ih_lo[0] + br2 + kb), a2);
            }
            store_sg(sg[0], a0, ln15, lhi);
            store_sg(sg[1], a1, ln15, lhi);
            store_sg(sg[2], a2, ln15, lhi);
        }
    } else {
        // gi input = h_{L-1}(t) just written this step (slot wsl)
        const u16* hi_hi = p.h_hi + (size_t)(2 * (L - 1) + wsl) * BH_;
        const u16* hi_lo = p.h_lo + (size_t)(2 * (L - 1) + wsl) * BH_;
        if (wave == 0) {
            const size_t br0 = (size_t)(0 * H_ + u0 + ln15) * H_;
            const size_t br1 = (size_t)(1 * H_ + u0 + ln15) * H_;
            f32x4 a0, a1;
            gemm_tile2<16>(hi_hi + arow, hi_lo + arow,
                           p.ih_hi[L] + br0, p.ih_lo[L] + br0,
                           p.ih_hi[L] + br1, p.ih_lo[L] + br1, lhi, a0, a1);
            store_sg(sg[0], a0, ln15, lhi);
            store_sg(sg[1], a1, ln15, lhi);
        } else if (wave == 1) {
            const size_t br0 = (size_t)(0 * H_ + u0 + ln15) * H_;
            const size_t br1 = (size_t)(1 * H_ + u0 + ln15) * H_;
            f32x4 a0, a1;
            gemm_tile2<16>(hp_hi + arow, hp_lo + arow,
                           p.hh_hi[L] + br0, p.hh_lo[L] + br0,
                           p.hh_hi[L] + br1, p.hh_lo[L] + br1, lhi, a0, a1);
            store_sg(sg[3], a0, ln15, lhi);
            store_sg(sg[4], a1, ln15, lhi);
        } else if (wave == 2) {
            const size_t br2 = (size_t)(2 * H_ + u0 + ln15) * H_;
            f32x4 a = gemm_tile<16>(hi_hi + arow, hi_lo + arow,
                                    p.ih_hi[L] + br2, p.ih_lo[L] + br2, lhi);
            store_sg(sg[2], a, ln15, lhi);
        } else {
            const size_t br2 = (size_t)(2 * H_ + u0 + ln15) * H_;
            f32x4 a = gemm_tile<16>(hp_hi + arow, hp_lo + arow,
                                    p.hh_hi[L] + br2, p.hh_lo[L] + br2, lhi);
            store_sg(sg[5], a, ln15, lhi);
        }
    }
    __syncthreads();
    // ---- elementwise GRU update (fp32), one (b,u) per thread ----
    {
        const int rb = tid & 15, uu = tid >> 4;
        const int u = u0 + uu, b = b0 + rb;
        const float ir  = sg[0][rb][uu] + p.b_ih[L][u];
        const float iz  = sg[1][rb][uu] + p.b_ih[L][H_ + u];
        const float in_ = sg[2][rb][uu] + p.b_ih[L][2 * H_ + u];
        const float hr  = sg[3][rb][uu] + p.b_hh[L][u];
        const float hz  = sg[4][rb][uu] + p.b_hh[L][H_ + u];
        const float hn  = sg[5][rb][uu] + p.b_hh[L][2 * H_ + u];
        const float r = 1.f / (1.f + expf(-(ir + hr)));
        const float z = 1.f / (1.f + expf(-(iz + hz)));
        const float n = tanhf(in_ + r * hn);
        const size_t hx = (size_t)b * H_ + u;
        const float hprev = bf2f_(hp_hi[hx]) + bf2f_(hp_lo[hx]);
        const float hnew = (1.f - z) * n + z * hprev;
        u16* ho_hi = p.h_hi + (size_t)(2 * L + wsl) * BH_;
        u16* ho_lo = p.h_lo + (size_t)(2 * L + wsl) * BH_;
        const u16 nh = f2bf_(hnew);
        ho_hi[hx] = nh;
        ho_lo[hx] = f2bf_(hnew - bf2f_(nh));
    }
    __syncthreads();
}

// ---------- output projection + softmax for one 16-batch slice ----------
__device__ void outproj_phase(const Params& p, int ty, int slot, int wg, int tid,
                              float (*slog)[33]) {
    const int wave = tid >> 6, lane = tid & 63;
    const int ln15 = lane & 15, lhi = lane >> 4;
    const int b0 = (wg - NWG_CELL) * 16;
    if (wave == 0) {
        const size_t arow = (size_t)(b0 + ln15) * H_;
        const u16* Ah = p.h_hi + (size_t)(4 + slot) * BH_ + arow;   // h3
        const u16* Al = p.h_lo + (size_t)(4 + slot) * BH_ + arow;
        f32x4 a0, a1;
        gemm_tile2<16>(Ah, Al,
                       p.wout_hi + (size_t)ln15 * H_,        p.wout_lo + (size_t)ln15 * H_,
                       p.wout_hi + (size_t)(16 + ln15) * H_, p.wout_lo + (size_t)(16 + ln15) * H_,
                       lhi, a0, a1);
#pragma unroll
        for (int q = 0; q < 4; ++q) {
            slog[lhi * 4 + q][ln15] = a0[q];
            slog[lhi * 4 + q][16 + ln15] = a1[q];
        }
    }
    __syncthreads();
    if (tid < 16) {
        float v[32];
        float m = -1e30f;
#pragma unroll
        for (int c = 0; c < 32; ++c) { v[c] = slog[tid][c] + p.b_out[c]; m = fmaxf(m, v[c]); }
        float s = 0.f;
#pragma unroll
        for (int c = 0; c < 32; ++c) { v[c] = expf(v[c] - m); s += v[c]; }
        const float inv = 1.f / s;
        float* yp = p.y + ((size_t)(b0 + tid) * T_ + ty) * C_;
#pragma unroll
        for (int c = 0; c < 32; ++c) yp[c] = v[c] * inv;
    }
    __syncthreads();
}

// ---------- persistent cooperative kernel: whole T-loop ----------
__global__ __launch_bounds__(256) void gru_coop(Params p) {
    cg::grid_group grid = cg::this_grid();
    __shared__ float sg[6][16][17];
    __shared__ float slog[16][33];
    const int wg = blockIdx.x, tid = threadIdx.x;
    for (int t = 0; t < T_; ++t) {
        const int rs = t & 1, wsl = rs ^ 1;
        // Phase A: cell 1 for (t)  ||  out-proj+softmax for (t-1)
        if (wg < NWG_CELL)      cell_phase<0>(p, t, rs, wsl, wg, tid, sg);
        else if (t > 0)         outproj_phase(p, t - 1, rs, wg, tid, slog);
        __threadfence(); grid.sync();
        if (wg < NWG_CELL)      cell_phase<1>(p, t, rs, wsl, wg, tid, sg);
        __threadfence(); grid.sync();
        if (wg < NWG_CELL)      cell_phase<2>(p, t, rs, wsl, wg, tid, sg);
        __threadfence(); grid.sync();
    }
    // epilogue: y for t = T-1 (h3 written to slot wsl(511) = 0)
    if (wg >= NWG_CELL) outproj_phase(p, T_ - 1, 0, wg, tid, slog);
}

extern "C" void kernel_launch(void* const* d_in, const int* in_sizes, int n_in,
                              void* d_out, int out_size, void* d_ws, size_t ws_size,
                              hipStream_t stream) {
    (void)in_sizes; (void)n_in; (void)out_size; (void)ws_size;

    const float* x      = (const float*)d_in[0];
    const float* h0[3]  = {(const float*)d_in[1], (const float*)d_in[2], (const float*)d_in[3]};
    const float* Wih[3] = {(const float*)d_in[4], (const float*)d_in[8], (const float*)d_in[12]};
    const float* Whh[3] = {(const float*)d_in[5], (const float*)d_in[9], (const float*)d_in[13]};
    const float* bih[3] = {(const float*)d_in[6], (const float*)d_in[10], (const float*)d_in[14]};
    const float* bhh[3] = {(const float*)d_in[7], (const float*)d_in[11], (const float*)d_in[15]};
    const float* Wout   = (const float*)d_in[16];
    const float* bout   = (const float*)d_in[17];

    // ---- ws layout (u16 units): split-bf16 planes for weights + h state ----
    u16* w = (u16*)d_ws;
    size_t off = 0;
    auto take = [&](size_t n) { u16* p = w + off; off += n; return p; };
    u16 *ihh[3], *ihl[3], *hhh[3], *hhl[3];
    const size_t szih[3] = {(size_t)3 * H_ * IN_, (size_t)3 * H_ * H_, (size_t)3 * H_ * H_};
    const size_t szhh = (size_t)3 * H_ * H_;
    for (int l = 0; l < 3; ++l) {
        ihh[l] = take(szih[l]); ihl[l] = take(szih[l]);
        hhh[l] = take(szhh);    hhl[l] = take(szhh);
    }
    u16* wouth = take((size_t)C_ * H_);
    u16* woutl = take((size_t)C_ * H_);
    u16* hhi = take((size_t)3 * 2 * BH_);
    u16* hlo = take((size_t)3 * 2 * BH_);
    // total: ~8.7M u16 = ~17.4 MB of ws

    auto split = [&](const float* src, u16* hi, u16* lo, int n) {
        split_kernel<<<dim3((n + 255) / 256), dim3(256), 0, stream>>>(src, hi, lo, n);
    };
    for (int l = 0; l < 3; ++l) {
        split(Wih[l], ihh[l], ihl[l], (int)szih[l]);
        split(Whh[l], hhh[l], hhl[l], (int)szhh);
    }
    split(Wout, wouth, woutl, C_ * H_);
    for (int l = 0; l < 3; ++l)   // h0 -> slot 0 of each layer
        split(h0[l], hhi + (size_t)(2 * l) * BH_, hlo + (size_t)(2 * l) * BH_, BH_);

    Params p;
    p.x = x;
    for (int l = 0; l < 3; ++l) {
        p.ih_hi[l] = ihh[l]; p.ih_lo[l] = ihl[l];
        p.hh_hi[l] = hhh[l]; p.hh_lo[l] = hhl[l];
        p.b_ih[l] = bih[l];  p.b_hh[l] = bhh[l];
    }
    p.wout_hi = wouth; p.wout_lo = woutl; p.b_out = bout;
    p.h_hi = hhi; p.h_lo = hlo;
    p.y = (float*)d_out;

    void* args[] = {&p};
    hipLaunchCooperativeKernel((void*)gru_coop, dim3(NWG_TOT), dim3(256), args, 0u, stream);
}

// Round 3
// 12394.963 us; speedup vs baseline: 4.8936x; 4.8936x over previous
//
#include <hip/hip_runtime.h>

typedef unsigned short u16;
typedef unsigned int u32;
typedef __attribute__((ext_vector_type(8))) short bf16x8;   // 8 bf16 in 4 VGPRs
typedef __attribute__((ext_vector_type(4))) float f32x4;

#define T_ 512
#define B_ 64
#define IN_ 128
#define H_ 512
#define C_ 32
#define BH_ (B_ * H_)        // 32768 elems per h plane
#define NWG_LAYER 64         // cell WGs per layer (each owns 32u x 16b)
#define NWG_CELL 192         // 3 layers x 64
#define NWG_TOT 196          // + 4 out-proj WGs  (<=256: coop launch validates)
#define NGRP 7               // ceil(196/32) arrive-counter groups
#define NT 515               // T + 3 pipeline ticks

// ---------- bf16 split helpers (RNE) ----------
__device__ inline u16 f2bf_(float f) {
    u32 u = __float_as_uint(f);
    u32 r = (u + 0x7FFFu + ((u >> 16) & 1u)) >> 16;
    return (u16)r;
}
__device__ inline float bf2f_(u16 h) { return __uint_as_float(((u32)h) << 16); }

// ---------- weight / h0 split kernel: fp32 -> (hi, lo) bf16 planes ----------
__global__ void split_kernel(const float* __restrict__ src, u16* __restrict__ hi,
                             u16* __restrict__ lo, int n) {
    int i = blockIdx.x * 256 + threadIdx.x;
    if (i < n) {
        float f = src[i];
        u16 h = f2bf_(f);
        hi[i] = h;
        lo[i] = f2bf_(f - bf2f_(h));
    }
}

// ---------- params ----------
struct Params {
    const float* x;
    const u16* ih_hi[3]; const u16* ih_lo[3];
    const u16* hh_hi[3]; const u16* hh_lo[3];
    const float* b_ih[3]; const float* b_hh[3];
    const u16* wout_hi; const u16* wout_lo;
    const float* b_out;
    u16* h_hi; u16* h_lo;   // [3 layers][2 slots][B*H]
    u32* bar;               // barrier state (zeroed per launch)
    float* y;               // [B][T][C]
};

// ---------- custom hierarchical grid barrier ----------
// bar[g*32]            : arrive counter for WG-group g (monotonic, 1 line apart)
// bar[NGRP*32]         : master counter (one inc per group per tick)
// bar[NGRP*32 + 32]    : generation word (== tick+1 when tick released)
__device__ inline void grid_barrier(u32* bar, int wg, int tid, u32 tick) {
    __syncthreads();
    if (tid == 0) {
        const int g = wg >> 5;
        const u32 gsz = (g == NGRP - 1) ? (u32)(NWG_TOT - 32 * (NGRP - 1)) : 32u;
        u32 old = __hip_atomic_fetch_add(&bar[g * 32], 1u,
                                         __ATOMIC_ACQ_REL, __HIP_MEMORY_SCOPE_AGENT);
        bool released = false;
        if (old == (tick + 1u) * gsz - 1u) {           // last of this group this tick
            u32 o2 = __hip_atomic_fetch_add(&bar[NGRP * 32], 1u,
                                            __ATOMIC_ACQ_REL, __HIP_MEMORY_SCOPE_AGENT);
            if (o2 == (tick + 1u) * (u32)NGRP - 1u) {  // last group overall
                __hip_atomic_store(&bar[NGRP * 32 + 32], tick + 1u,
                                   __ATOMIC_RELEASE, __HIP_MEMORY_SCOPE_AGENT);
                released = true;
            }
        }
        if (!released) {
            while (__hip_atomic_load(&bar[NGRP * 32 + 32],
                                     __ATOMIC_RELAXED, __HIP_MEMORY_SCOPE_AGENT) < tick + 1u) {
                __builtin_amdgcn_s_sleep(1);
            }
            __builtin_amdgcn_fence(__ATOMIC_ACQUIRE, "agent");
        }
    }
    __syncthreads();
}

// ---------- MFMA helpers ----------
__device__ inline bf16x8 ld8(const u16* p) { return *reinterpret_cast<const bf16x8*>(p); }

__device__ inline f32x4 mfma3(bf16x8 ah, bf16x8 al, bf16x8 bh, bf16x8 bl, f32x4 c) {
    c = __builtin_amdgcn_mfma_f32_16x16x32_bf16(ah, bh, c, 0, 0, 0);
    c = __builtin_amdgcn_mfma_f32_16x16x32_bf16(al, bh, c, 0, 0, 0);
    c = __builtin_amdgcn_mfma_f32_16x16x32_bf16(ah, bl, c, 0, 0, 0);
    return c;
}

// one shared A, three B rows -> three 16x16 tiles
template <int NKT>
__device__ inline void gemm_tile3(const u16* Ah, const u16* Al,
                                  const u16* B0h, const u16* B0l,
                                  const u16* B1h, const u16* B1l,
                                  const u16* B2h, const u16* B2l,
                                  int lhi, f32x4& o0, f32x4& o1, f32x4& o2) {
    f32x4 a0 = {0.f,0.f,0.f,0.f}, a1 = {0.f,0.f,0.f,0.f}, a2 = {0.f,0.f,0.f,0.f};
#pragma unroll
    for (int kt = 0; kt < NKT; ++kt) {
        const int kb = kt * 32 + lhi * 8;
        bf16x8 ah = ld8(Ah + kb), al = ld8(Al + kb);
        a0 = mfma3(ah, al, ld8(B0h + kb), ld8(B0l + kb), a0);
        a1 = mfma3(ah, al, ld8(B1h + kb), ld8(B1l + kb), a1);
        a2 = mfma3(ah, al, ld8(B2h + kb), ld8(B2l + kb), a2);
    }
    o0 = a0; o1 = a1; o2 = a2;
}

template <int NKT>
__device__ inline void gemm_tile2(const u16* Ah, const u16* Al,
                                  const u16* B0h, const u16* B0l,
                                  const u16* B1h, const u16* B1l,
                                  int lhi, f32x4& o0, f32x4& o1) {
    f32x4 a0 = {0.f, 0.f, 0.f, 0.f}, a1 = {0.f, 0.f, 0.f, 0.f};
#pragma unroll
    for (int kt = 0; kt < NKT; ++kt) {
        const int kb = kt * 32 + lhi * 8;
        bf16x8 ah = ld8(Ah + kb), al = ld8(Al + kb);
        a0 = mfma3(ah, al, ld8(B0h + kb), ld8(B0l + kb), a0);
        a1 = mfma3(ah, al, ld8(B1h + kb), ld8(B1l + kb), a1);
    }
    o0 = a0; o1 = a1;
}

// C/D layout (m89-verified): col = lane&15, row = (lane>>4)*4 + reg
__device__ inline void store_sg(float (&dst)[16][33], f32x4 a, int col, int lhi) {
#pragma unroll
    for (int q = 0; q < 4; ++q) dst[lhi * 4 + q][col] = a[q];
}

// ---------- one GRU cell phase for one WG (wgl in [0,64)) ----------
// WG owns a 32u x 16b output tile: 6 gates x 2 u-subtiles = 12 16x16 tiles,
// 3 per wave (waves 0-1: gi gates, shared A = layer input; waves 2-3: gh, A = h_prev).
// h(tau) lives in slot (tau+1)&1. rs = t&1 (read own h(t-1)), wsl = rs^1 (write h(t)).
template <int L>
__device__ void cell_phase(const Params& p, int t, int rs, int wsl, int wgl, int tid,
                           float (*sg)[16][33]) {
    const int wave = tid >> 6, lane = tid & 63;
    const int ln15 = lane & 15, lhi = lane >> 4;
    const int ug = wgl & 15, mb = wgl >> 4;   // stride-16 ids share XCD -> weight L2 reuse
    const int u0 = ug * 32, b0 = mb * 16;
    const size_t arow = (size_t)(b0 + ln15) * H_;

    const u16* hp_hi = p.h_hi + (size_t)(2 * L + rs) * BH_;   // h_own(t-1)
    const u16* hp_lo = p.h_lo + (size_t)(2 * L + rs) * BH_;

    // this wave's 3 tiles: tt = wave*3 + j ; gate g = tt>>1, u-subtile us = tt&1
    const int tt0 = wave * 3;
    const int gA = (tt0    ) >> 1, cA = ((tt0    ) & 1) * 16 + ln15;
    const int gB = (tt0 + 1) >> 1, cB = ((tt0 + 1) & 1) * 16 + ln15;
    const int gC = (tt0 + 2) >> 1, cC = ((tt0 + 2) & 1) * 16 + ln15;

    f32x4 oA, oB, oC;
    if (wave < 2) {
        // gi gates (g in 0..2): B = W_ih rows g*H + u0 + c
        if (L == 0) {
            // A = x_t rows, fp32 split on the fly; K = 128
            const float* xr = p.x + (size_t)(b0 + ln15) * (T_ * IN_) + (size_t)t * IN_;
            const u16* B0h = p.ih_hi[0] + (size_t)(gA * H_ + u0 + cA - ln15 + ln15) * IN_;
            const u16* B0l = p.ih_lo[0] + (size_t)(gA * H_ + u0 + cA) * IN_;
            const u16* B1h = p.ih_hi[0] + (size_t)(gB * H_ + u0 + cB) * IN_;
            const u16* B1l = p.ih_lo[0] + (size_t)(gB * H_ + u0 + cB) * IN_;
            const u16* B2h = p.ih_hi[0] + (size_t)(gC * H_ + u0 + cC) * IN_;
            const u16* B2l = p.ih_lo[0] + (size_t)(gC * H_ + u0 + cC) * IN_;
            B0h = p.ih_hi[0] + (size_t)(gA * H_ + u0 + cA) * IN_;
            f32x4 a0 = {0.f,0.f,0.f,0.f}, a1 = {0.f,0.f,0.f,0.f}, a2 = {0.f,0.f,0.f,0.f};
#pragma unroll
            for (int kt = 0; kt < 4; ++kt) {
                const int kb = kt * 32 + lhi * 8;
                bf16x8 ah, al;
#pragma unroll
                for (int j = 0; j < 8; ++j) {
                    float f = xr[kb + j];
                    u16 hb = f2bf_(f);
                    ah[j] = (short)hb;
                    al[j] = (short)f2bf_(f - bf2f_(hb));
                }
                a0 = mfma3(ah, al, ld8(B0h + kb), ld8(B0l + kb), a0);
                a1 = mfma3(ah, al, ld8(B1h + kb), ld8(B1l + kb), a1);
                a2 = mfma3(ah, al, ld8(B2h + kb), ld8(B2l + kb), a2);
            }
            oA = a0; oB = a1; oC = a2;
        } else {
            // A = h_{L-1}(t), written by layer L-1 last tick (slot wsl); K = 512
            const u16* Ah = p.h_hi + (size_t)(2 * (L - 1) + wsl) * BH_ + arow;
            const u16* Al = p.h_lo + (size_t)(2 * (L - 1) + wsl) * BH_ + arow;
            gemm_tile3<16>(Ah, Al,
                           p.ih_hi[L] + (size_t)(gA * H_ + u0 + cA) * H_,
                           p.ih_lo[L] + (size_t)(gA * H_ + u0 + cA) * H_,
                           p.ih_hi[L] + (size_t)(gB * H_ + u0 + cB) * H_,
                           p.ih_lo[L] + (size_t)(gB * H_ + u0 + cB) * H_,
                           p.ih_hi[L] + (size_t)(gC * H_ + u0 + cC) * H_,
                           p.ih_lo[L] + (size_t)(gC * H_ + u0 + cC) * H_,
                           lhi, oA, oB, oC);
        }
    } else {
        // gh gates (g-3 in 0..2): A = h_own(t-1); B = W_hh rows (g-3)*H + u0 + c
        gemm_tile3<16>(hp_hi + arow, hp_lo + arow,
                       p.hh_hi[L] + (size_t)((gA - 3) * H_ + u0 + cA) * H_,
                       p.hh_lo[L] + (size_t)((gA - 3) * H_ + u0 + cA) * H_,
                       p.hh_hi[L] + (size_t)((gB - 3) * H_ + u0 + cB) * H_,
                       p.hh_lo[L] + (size_t)((gB - 3) * H_ + u0 + cB) * H_,
                       p.hh_hi[L] + (size_t)((gC - 3) * H_ + u0 + cC) * H_,
                       p.hh_lo[L] + (size_t)((gC - 3) * H_ + u0 + cC) * H_,
                       lhi, oA, oB, oC);
    }
    store_sg(sg[gA], oA, cA, lhi);
    store_sg(sg[gB], oB, cB, lhi);
    store_sg(sg[gC], oC, cC, lhi);
    __syncthreads();
    // ---- elementwise GRU update (fp32), two (b,u) per thread ----
    {
        const int rb = tid & 15, uu = tid >> 4;
        u16* ho_hi = p.h_hi + (size_t)(2 * L + wsl) * BH_;
        u16* ho_lo = p.h_lo + (size_t)(2 * L + wsl) * BH_;
#pragma unroll
        for (int half = 0; half < 2; ++half) {
            const int uc = uu + half * 16;
            const int u = u0 + uc, b = b0 + rb;
            const float ir  = sg[0][rb][uc] + p.b_ih[L][u];
            const float iz  = sg[1][rb][uc] + p.b_ih[L][H_ + u];
            const float in_ = sg[2][rb][uc] + p.b_ih[L][2 * H_ + u];
            const float hr  = sg[3][rb][uc] + p.b_hh[L][u];
            const float hz  = sg[4][rb][uc] + p.b_hh[L][H_ + u];
            const float hn  = sg[5][rb][uc] + p.b_hh[L][2 * H_ + u];
            const float r = 1.f / (1.f + expf(-(ir + hr)));
            const float z = 1.f / (1.f + expf(-(iz + hz)));
            const float n = tanhf(in_ + r * hn);
            const size_t hx = (size_t)b * H_ + u;
            const float hprev = bf2f_(hp_hi[hx]) + bf2f_(hp_lo[hx]);
            const float hnew = (1.f - z) * n + z * hprev;
            const u16 nh = f2bf_(hnew);
            ho_hi[hx] = nh;
            ho_lo[hx] = f2bf_(hnew - bf2f_(nh));
        }
    }
}

// ---------- output projection + softmax for one 16-batch slice ----------
__device__ void outproj_phase(const Params& p, int ty, int slot, int wg, int tid,
                              float (*slog)[33]) {
    const int wave = tid >> 6, lane = tid & 63;
    const int ln15 = lane & 15, lhi = lane >> 4;
    const int b0 = (wg - NWG_CELL) * 16;
    if (wave == 0) {
        const size_t arow = (size_t)(b0 + ln15) * H_;
        const u16* Ah = p.h_hi + (size_t)(4 + slot) * BH_ + arow;   // h3(ty)
        const u16* Al = p.h_lo + (size_t)(4 + slot) * BH_ + arow;
        f32x4 a0, a1;
        gemm_tile2<16>(Ah, Al,
                       p.wout_hi + (size_t)ln15 * H_,        p.wout_lo + (size_t)ln15 * H_,
                       p.wout_hi + (size_t)(16 + ln15) * H_, p.wout_lo + (size_t)(16 + ln15) * H_,
                       lhi, a0, a1);
#pragma unroll
        for (int q = 0; q < 4; ++q) {
            slog[lhi * 4 + q][ln15] = a0[q];
            slog[lhi * 4 + q][16 + ln15] = a1[q];
        }
    }
    __syncthreads();
    if (tid < 16) {
        float v[32];
        float m = -1e30f;
#pragma unroll
        for (int c = 0; c < 32; ++c) { v[c] = slog[tid][c] + p.b_out[c]; m = fmaxf(m, v[c]); }
        float s = 0.f;
#pragma unroll
        for (int c = 0; c < 32; ++c) { v[c] = expf(v[c] - m); s += v[c]; }
        const float inv = 1.f / s;
        float* yp = p.y + ((size_t)(b0 + tid) * T_ + ty) * C_;
#pragma unroll
        for (int c = 0; c < 32; ++c) yp[c] = v[c] * inv;
    }
}

// ---------- persistent kernel: layer-pipelined T-loop ----------
// tick u: layer L computes t = u - L; out-proj computes t = u - 3.
// One grid barrier per tick (515 total).
__global__ __launch_bounds__(256) void gru_pipe(Params p) {
    __shared__ float sg[6][16][33];
    __shared__ float slog[16][33];
    const int wg = blockIdx.x, tid = threadIdx.x;
    for (int u = 0; u < NT; ++u) {
        if (wg < NWG_CELL) {
            const int L = wg >> 6, wgl = wg & 63;
            const int t = u - L;
            if (t >= 0 && t < T_) {
                const int rs = t & 1, wsl = rs ^ 1;
                if (L == 0)      cell_phase<0>(p, t, rs, wsl, wgl, tid, sg);
                else if (L == 1) cell_phase<1>(p, t, rs, wsl, wgl, tid, sg);
                else             cell_phase<2>(p, t, rs, wsl, wgl, tid, sg);
            }
        } else {
            const int t = u - 3;
            if (t >= 0) outproj_phase(p, t, (t + 1) & 1, wg, tid, slog);
        }
        grid_barrier(p.bar, wg, tid, (u32)u);
    }
}

extern "C" void kernel_launch(void* const* d_in, const int* in_sizes, int n_in,
                              void* d_out, int out_size, void* d_ws, size_t ws_size,
                              hipStream_t stream) {
    (void)in_sizes; (void)n_in; (void)out_size; (void)ws_size;

    const float* x      = (const float*)d_in[0];
    const float* h0[3]  = {(const float*)d_in[1], (const float*)d_in[2], (const float*)d_in[3]};
    const float* Wih[3] = {(const float*)d_in[4], (const float*)d_in[8], (const float*)d_in[12]};
    const float* Whh[3] = {(const float*)d_in[5], (const float*)d_in[9], (const float*)d_in[13]};
    const float* bih[3] = {(const float*)d_in[6], (const float*)d_in[10], (const float*)d_in[14]};
    const float* bhh[3] = {(const float*)d_in[7], (const float*)d_in[11], (const float*)d_in[15]};
    const float* Wout   = (const float*)d_in[16];
    const float* bout   = (const float*)d_in[17];

    // ---- ws layout (u16 units): split-bf16 planes for weights + h state + barrier ----
    u16* w = (u16*)d_ws;
    size_t off = 0;
    auto take = [&](size_t n) { u16* p = w + off; off += n; return p; };
    u16 *ihh[3], *ihl[3], *hhh[3], *hhl[3];
    const size_t szih[3] = {(size_t)3 * H_ * IN_, (size_t)3 * H_ * H_, (size_t)3 * H_ * H_};
    const size_t szhh = (size_t)3 * H_ * H_;
    for (int l = 0; l < 3; ++l) {
        ihh[l] = take(szih[l]); ihl[l] = take(szih[l]);
        hhh[l] = take(szhh);    hhl[l] = take(szhh);
    }
    u16* wouth = take((size_t)C_ * H_);
    u16* woutl = take((size_t)C_ * H_);
    u16* hhi = take((size_t)3 * 2 * BH_);
    u16* hlo = take((size_t)3 * 2 * BH_);
    off = (off + 255) & ~(size_t)255;               // align barrier to 512B
    u32* bar = (u32*)take(2 * ((NGRP + 2) * 32));
    const size_t bar_bytes = (size_t)(NGRP + 2) * 32 * sizeof(u32);

    hipMemsetAsync(bar, 0, bar_bytes, stream);      // reset barrier every launch (graph-safe)

    auto split = [&](const float* src, u16* hi, u16* lo, int n) {
        split_kernel<<<dim3((n + 255) / 256), dim3(256), 0, stream>>>(src, hi, lo, n);
    };
    for (int l = 0; l < 3; ++l) {
        split(Wih[l], ihh[l], ihl[l], (int)szih[l]);
        split(Whh[l], hhh[l], hhl[l], (int)szhh);
    }
    split(Wout, wouth, woutl, C_ * H_);
    for (int l = 0; l < 3; ++l)   // h0 -> slot 0 of each layer
        split(h0[l], hhi + (size_t)(2 * l) * BH_, hlo + (size_t)(2 * l) * BH_, BH_);

    Params p;
    p.x = x;
    for (int l = 0; l < 3; ++l) {
        p.ih_hi[l] = ihh[l]; p.ih_lo[l] = ihl[l];
        p.hh_hi[l] = hhh[l]; p.hh_lo[l] = hhl[l];
        p.b_ih[l] = bih[l];  p.b_hh[l] = bhh[l];
    }
    p.wout_hi = wouth; p.wout_lo = woutl; p.b_out = bout;
    p.h_hi = hhi; p.h_lo = hlo;
    p.bar = bar;
    p.y = (float*)d_out;

    void* args[] = {&p};
    hipError_t err = hipLaunchCooperativeKernel((void*)gru_pipe, dim3(NWG_TOT), dim3(256),
                                                args, 0u, stream);
    if (err != hipSuccess) {
        // 196 blocks x 4 waves trivially co-reside on 256 CUs; custom barrier
        // doesn't require cooperative semantics, only co-residency.
        gru_pipe<<<dim3(NWG_TOT), dim3(256), 0, stream>>>(p);
    }
}

// Round 4
// 7625.598 us; speedup vs baseline: 7.9543x; 1.6254x over previous
//
#include <hip/hip_runtime.h>

typedef unsigned short u16;
typedef unsigned int u32;
typedef unsigned long long u64;
typedef __attribute__((ext_vector_type(8))) short bf16x8;   // 8 bf16 in 4 VGPRs
typedef __attribute__((ext_vector_type(4))) float f32x4;

#define T_ 512
#define B_ 64
#define IN_ 128
#define H_ 512
#define C_ 32
#define BH_ (B_ * H_)        // 32768 elems per h plane
#define NWG_LAYER 64         // cell WGs per layer (each owns 32u x 16b)
#define NWG_CELL 192         // 3 layers x 64
#define NWG_TOT 196          // + 4 out-proj WGs  (<=256: coop launch validates)
#define NGRP 7               // ceil(196/32) arrive-counter groups
#define NT 515               // T + 3 pipeline ticks

// ---------- bf16 split helpers (RNE) ----------
__device__ inline u16 f2bf_(float f) {
    u32 u = __float_as_uint(f);
    u32 r = (u + 0x7FFFu + ((u >> 16) & 1u)) >> 16;
    return (u16)r;
}
__device__ inline float bf2f_(u16 h) { return __uint_as_float(((u32)h) << 16); }

// ---------- LLC-direct (agent-scope, relaxed) access for h exchange ----------
// Relaxed atomics carry NO cache-maintenance (no buffer_wbl2/inv): stores are
// write-through to the coherence point, loads read it directly. Weights keep
// normal cached loads and stay L2-resident across all 515 ticks.
__device__ inline u64 ld_llc_u64(const u64* p) {
    return __hip_atomic_load((u64*)p, __ATOMIC_RELAXED, __HIP_MEMORY_SCOPE_AGENT);
}
__device__ inline void st_llc_u32(u32* p, u32 v) {
    __hip_atomic_store(p, v, __ATOMIC_RELAXED, __HIP_MEMORY_SCOPE_AGENT);
}

// ---------- weight / h0 split kernel: fp32 -> (hi, lo) bf16 planes ----------
__global__ void split_kernel(const float* __restrict__ src, u16* __restrict__ hi,
                             u16* __restrict__ lo, int n) {
    int i = blockIdx.x * 256 + threadIdx.x;
    if (i < n) {
        float f = src[i];
        u16 h = f2bf_(f);
        hi[i] = h;
        lo[i] = f2bf_(f - bf2f_(h));
    }
}

// ---------- params ----------
struct Params {
    const float* x;
    const u16* ih_hi[3]; const u16* ih_lo[3];
    const u16* hh_hi[3]; const u16* hh_lo[3];
    const float* b_ih[3]; const float* b_hh[3];
    const u16* wout_hi; const u16* wout_lo;
    const float* b_out;
    u16* h_hi; u16* h_lo;   // [3 layers][2 slots][B*H]
    u32* bar;               // barrier state (zeroed per launch)
    float* y;               // [B][T][C]
};

// ---------- fully-relaxed hierarchical grid barrier ----------
// Causality: __syncthreads drains vmcnt (h sc-stores reach LLC) before tid0's
// arrive RMW (at LLC); gen store happens after all arrives; consumers' h loads
// are LLC-direct and issue in-order after the poll exits. No fences anywhere.
__device__ inline void grid_barrier(u32* bar, int wg, int tid, u32 tick) {
    __syncthreads();
    if (tid == 0) {
        const int g = wg >> 5;
        const u32 gsz = (g == NGRP - 1) ? (u32)(NWG_TOT - 32 * (NGRP - 1)) : 32u;
        u32 old = __hip_atomic_fetch_add(&bar[g * 32], 1u,
                                         __ATOMIC_RELAXED, __HIP_MEMORY_SCOPE_AGENT);
        if (old == (tick + 1u) * gsz - 1u) {           // last of this group this tick
            u32 o2 = __hip_atomic_fetch_add(&bar[NGRP * 32], 1u,
                                            __ATOMIC_RELAXED, __HIP_MEMORY_SCOPE_AGENT);
            if (o2 == (tick + 1u) * (u32)NGRP - 1u)    // last group overall
                __hip_atomic_store(&bar[NGRP * 32 + 32], tick + 1u,
                                   __ATOMIC_RELAXED, __HIP_MEMORY_SCOPE_AGENT);
        }
        while (__hip_atomic_load(&bar[NGRP * 32 + 32],
                                 __ATOMIC_RELAXED, __HIP_MEMORY_SCOPE_AGENT) < tick + 1u) {
            __builtin_amdgcn_s_sleep(1);
        }
    }
    __syncthreads();
}

// ---------- MFMA helpers ----------
__device__ inline bf16x8 ld8(const u16* p) { return *reinterpret_cast<const bf16x8*>(p); }

// staged-h LDS read: [16][512] u16 rows, byte ^= (row&7)<<4 swizzle (G4 fix:
// rows 0..7 spread over 8 16B slots -> 2 lanes/bank = free)
__device__ inline bf16x8 ld8_lds(const u16* s, int row, int kb) {
    const int bo = (row << 10) + (((kb) << 1) ^ ((row & 7) << 4));
    return *reinterpret_cast<const bf16x8*>((const char*)s + bo);
}

__device__ inline f32x4 mfma3(bf16x8 ah, bf16x8 al, bf16x8 bh, bf16x8 bl, f32x4 c) {
    c = __builtin_amdgcn_mfma_f32_16x16x32_bf16(ah, bh, c, 0, 0, 0);
    c = __builtin_amdgcn_mfma_f32_16x16x32_bf16(al, bh, c, 0, 0, 0);
    c = __builtin_amdgcn_mfma_f32_16x16x32_bf16(ah, bl, c, 0, 0, 0);
    return c;
}

// A from staged LDS (row = ln15), three weight-B streams from global (L2-resident)
template <int NKT>
__device__ inline void gemm_tile3_ldsA(const u16* sAh, const u16* sAl, int row,
                                       const u16* B0h, const u16* B0l,
                                       const u16* B1h, const u16* B1l,
                                       const u16* B2h, const u16* B2l,
                                       int lhi, f32x4& o0, f32x4& o1, f32x4& o2) {
    f32x4 a0 = {0.f,0.f,0.f,0.f}, a1 = {0.f,0.f,0.f,0.f}, a2 = {0.f,0.f,0.f,0.f};
#pragma unroll
    for (int kt = 0; kt < NKT; ++kt) {
        const int kb = kt * 32 + lhi * 8;
        bf16x8 ah = ld8_lds(sAh, row, kb), al = ld8_lds(sAl, row, kb);
        a0 = mfma3(ah, al, ld8(B0h + kb), ld8(B0l + kb), a0);
        a1 = mfma3(ah, al, ld8(B1h + kb), ld8(B1l + kb), a1);
        a2 = mfma3(ah, al, ld8(B2h + kb), ld8(B2l + kb), a2);
    }
    o0 = a0; o1 = a1; o2 = a2;
}

template <int NKT>
__device__ inline void gemm_tile2_ldsA(const u16* sAh, const u16* sAl, int row,
                                       const u16* B0h, const u16* B0l,
                                       const u16* B1h, const u16* B1l,
                                       int lhi, f32x4& o0, f32x4& o1) {
    f32x4 a0 = {0.f,0.f,0.f,0.f}, a1 = {0.f,0.f,0.f,0.f};
#pragma unroll
    for (int kt = 0; kt < NKT; ++kt) {
        const int kb = kt * 32 + lhi * 8;
        bf16x8 ah = ld8_lds(sAh, row, kb), al = ld8_lds(sAl, row, kb);
        a0 = mfma3(ah, al, ld8(B0h + kb), ld8(B0l + kb), a0);
        a1 = mfma3(ah, al, ld8(B1h + kb), ld8(B1l + kb), a1);
    }
    o0 = a0; o1 = a1;
}

// ---------- stage one h block (16 rows x 512, hi+lo) global->LDS ----------
// Batched LLC loads (16 independent u64s in flight), then swizzled ds_writes.
__device__ inline void stage_h(const u16* ghi, const u16* glo,
                               u16* shi, u16* slo, int b0, int tid) {
    u64 rh[8], rl[8];
#pragma unroll
    for (int k = 0; k < 8; ++k) {
        const int idx = tid + (k << 8);
        const int row = idx >> 7;                  // 128 u64 per 512-u16 row
        const u64* srch = (const u64*)(ghi + (size_t)(b0 + row) * H_) + (idx & 127);
        const u64* srcl = (const u64*)(glo + (size_t)(b0 + row) * H_) + (idx & 127);
        rh[k] = ld_llc_u64(srch);
        rl[k] = ld_llc_u64(srcl);
    }
#pragma unroll
    for (int k = 0; k < 8; ++k) {
        const int idx = tid + (k << 8);
        const int row = idx >> 7;
        const int so = (row << 10) + ((((idx & 127) << 3)) ^ ((row & 7) << 4));
        *(u64*)((char*)shi + so) = rh[k];
        *(u64*)((char*)slo + so) = rl[k];
    }
}

// C/D layout (m89-verified): col = lane&15, row = (lane>>4)*4 + reg
__device__ inline void store_sg(float (&dst)[16][33], f32x4 a, int col, int lhi) {
#pragma unroll
    for (int q = 0; q < 4; ++q) dst[lhi * 4 + q][col] = a[q];
}

// ---------- one GRU cell phase for one WG (wgl in [0,64)) ----------
// WG owns 32u x 16b: 6 gates x 2 u-subtiles = 12 16x16 tiles, 3 per wave.
// waves 0-1: gi (A = layer input); waves 2-3: gh (A = h_own(t-1)).
// h(tau) in slot (tau+1)&1. rs = t&1 (read h(t-1)), wsl = rs^1 (write h(t)).
template <int L>
__device__ void cell_phase(const Params& p, int t, int rs, int wsl, int wgl, int tid,
                           float (*sg)[16][33], u16 (*hs)[8192]) {
    const int wave = tid >> 6, lane = tid & 63;
    const int ln15 = lane & 15, lhi = lane >> 4;
    const int ug = wgl & 15, mb = wgl >> 4;   // stride-16 ids share XCD -> weight L2 reuse
    const int u0 = ug * 32, b0 = mb * 16;

    const u16* hp_hi = p.h_hi + (size_t)(2 * L + rs) * BH_;   // h_own(t-1)
    const u16* hp_lo = p.h_lo + (size_t)(2 * L + rs) * BH_;

    // ---- stage h blocks via LLC into LDS ----
    stage_h(hp_hi, hp_lo, hs[0], hs[1], b0, tid);
    if (L > 0) {
        const u16* hi_hi = p.h_hi + (size_t)(2 * (L - 1) + wsl) * BH_;  // h_{L-1}(t)
        const u16* hi_lo = p.h_lo + (size_t)(2 * (L - 1) + wsl) * BH_;
        stage_h(hi_hi, hi_lo, hs[2], hs[3], b0, tid);
    }
    __syncthreads();

    // this wave's 3 tiles: tt = wave*3 + j ; gate g = tt>>1, u-subtile = tt&1
    const int tt0 = wave * 3;
    const int gA = (tt0    ) >> 1, cA = ((tt0    ) & 1) * 16 + ln15;
    const int gB = (tt0 + 1) >> 1, cB = ((tt0 + 1) & 1) * 16 + ln15;
    const int gC = (tt0 + 2) >> 1, cC = ((tt0 + 2) & 1) * 16 + ln15;

    f32x4 oA, oB, oC;
    if (wave < 2) {
        if (L == 0) {
            // A = x_t rows (normal cached loads), fp32 split on the fly; K = 128
            const float* xr = p.x + (size_t)(b0 + ln15) * (T_ * IN_) + (size_t)t * IN_;
            const u16* B0h = p.ih_hi[0] + (size_t)(gA * H_ + u0 + cA) * IN_;
            const u16* B0l = p.ih_lo[0] + (size_t)(gA * H_ + u0 + cA) * IN_;
            const u16* B1h = p.ih_hi[0] + (size_t)(gB * H_ + u0 + cB) * IN_;
            const u16* B1l = p.ih_lo[0] + (size_t)(gB * H_ + u0 + cB) * IN_;
            const u16* B2h = p.ih_hi[0] + (size_t)(gC * H_ + u0 + cC) * IN_;
            const u16* B2l = p.ih_lo[0] + (size_t)(gC * H_ + u0 + cC) * IN_;
            f32x4 a0 = {0.f,0.f,0.f,0.f}, a1 = {0.f,0.f,0.f,0.f}, a2 = {0.f,0.f,0.f,0.f};
#pragma unroll
            for (int kt = 0; kt < 4; ++kt) {
                const int kb = kt * 32 + lhi * 8;
                bf16x8 ah, al;
#pragma unroll
                for (int j = 0; j < 8; ++j) {
                    float f = xr[kb + j];
                    u16 hb = f2bf_(f);
                    ah[j] = (short)hb;
                    al[j] = (short)f2bf_(f - bf2f_(hb));
                }
                a0 = mfma3(ah, al, ld8(B0h + kb), ld8(B0l + kb), a0);
                a1 = mfma3(ah, al, ld8(B1h + kb), ld8(B1l + kb), a1);
                a2 = mfma3(ah, al, ld8(B2h + kb), ld8(B2l + kb), a2);
            }
            oA = a0; oB = a1; oC = a2;
        } else {
            // A = h_{L-1}(t) from LDS; K = 512
            gemm_tile3_ldsA<16>(hs[2], hs[3], ln15,
                                p.ih_hi[L] + (size_t)(gA * H_ + u0 + cA) * H_,
                                p.ih_lo[L] + (size_t)(gA * H_ + u0 + cA) * H_,
                                p.ih_hi[L] + (size_t)(gB * H_ + u0 + cB) * H_,
                                p.ih_lo[L] + (size_t)(gB * H_ + u0 + cB) * H_,
                                p.ih_hi[L] + (size_t)(gC * H_ + u0 + cC) * H_,
                                p.ih_lo[L] + (size_t)(gC * H_ + u0 + cC) * H_,
                                lhi, oA, oB, oC);
        }
    } else {
        // gh gates: A = h_own(t-1) from LDS
        gemm_tile3_ldsA<16>(hs[0], hs[1], ln15,
                            p.hh_hi[L] + (size_t)((gA - 3) * H_ + u0 + cA) * H_,
                            p.hh_lo[L] + (size_t)((gA - 3) * H_ + u0 + cA) * H_,
                            p.hh_hi[L] + (size_t)((gB - 3) * H_ + u0 + cB) * H_,
                            p.hh_lo[L] + (size_t)((gB - 3) * H_ + u0 + cB) * H_,
                            p.hh_hi[L] + (size_t)((gC - 3) * H_ + u0 + cC) * H_,
                            p.hh_lo[L] + (size_t)((gC - 3) * H_ + u0 + cC) * H_,
                            lhi, oA, oB, oC);
    }
    store_sg(sg[gA], oA, cA - ln15 + ln15, lhi);   // col = (tt&1)*16 + ln15
    store_sg(sg[gB], oB, cB, lhi);
    store_sg(sg[gC], oC, cC, lhi);
    __syncthreads();

    // ---- elementwise GRU update (fp32): 2 consecutive u per thread ----
    {
        const int rb = tid & 15, uu = tid >> 4;
        const int colu = uu * 2;                    // even local col
        const int gcol = u0 + colu;
        const int bo = (gcol * 2) ^ ((rb & 7) << 4);
        const u32 hp2h = *(const u32*)((const char*)hs[0] + (rb << 10) + bo);
        const u32 hp2l = *(const u32*)((const char*)hs[1] + (rb << 10) + bo);
        u32 packh = 0, packl = 0;
#pragma unroll
        for (int half = 0; half < 2; ++half) {
            const int uc = colu + half;
            const int u = u0 + uc;
            const float ir  = sg[0][rb][uc] + p.b_ih[L][u];
            const float iz  = sg[1][rb][uc] + p.b_ih[L][H_ + u];
            const float in_ = sg[2][rb][uc] + p.b_ih[L][2 * H_ + u];
            const float hr  = sg[3][rb][uc] + p.b_hh[L][u];
            const float hz  = sg[4][rb][uc] + p.b_hh[L][H_ + u];
            const float hn  = sg[5][rb][uc] + p.b_hh[L][2 * H_ + u];
            const float r = 1.f / (1.f + expf(-(ir + hr)));
            const float z = 1.f / (1.f + expf(-(iz + hz)));
            const float n = tanhf(in_ + r * hn);
            const float hprev = bf2f_((u16)((half ? (hp2h >> 16) : hp2h) & 0xffffu))
                              + bf2f_((u16)((half ? (hp2l >> 16) : hp2l) & 0xffffu));
            const float hnew = (1.f - z) * n + z * hprev;
            const u16 nh = f2bf_(hnew);
            const u16 nl = f2bf_(hnew - bf2f_(nh));
            packh |= (u32)nh << (16 * half);
            packl |= (u32)nl << (16 * half);
        }
        u16* ho_hi = p.h_hi + (size_t)(2 * L + wsl) * BH_;
        u16* ho_lo = p.h_lo + (size_t)(2 * L + wsl) * BH_;
        const size_t hx = (size_t)(b0 + rb) * H_ + gcol;
        st_llc_u32((u32*)(ho_hi + hx), packh);      // write-through to LLC
        st_llc_u32((u32*)(ho_lo + hx), packl);
    }
}

// ---------- output projection + softmax for one 16-batch slice ----------
__device__ void outproj_phase(const Params& p, int ty, int slot, int wg, int tid,
                              float (*slog)[33], u16 (*hs)[8192]) {
    const int wave = tid >> 6, lane = tid & 63;
    const int ln15 = lane & 15, lhi = lane >> 4;
    const int b0 = (wg - NWG_CELL) * 16;
    const u16* Ah = p.h_hi + (size_t)(4 + slot) * BH_;   // h3(ty)
    const u16* Al = p.h_lo + (size_t)(4 + slot) * BH_;
    stage_h(Ah, Al, hs[0], hs[1], b0, tid);
    __syncthreads();
    if (wave == 0) {
        f32x4 a0, a1;
        gemm_tile2_ldsA<16>(hs[0], hs[1], ln15,
                            p.wout_hi + (size_t)ln15 * H_,        p.wout_lo + (size_t)ln15 * H_,
                            p.wout_hi + (size_t)(16 + ln15) * H_, p.wout_lo + (size_t)(16 + ln15) * H_,
                            lhi, a0, a1);
#pragma unroll
        for (int q = 0; q < 4; ++q) {
            slog[lhi * 4 + q][ln15] = a0[q];
            slog[lhi * 4 + q][16 + ln15] = a1[q];
        }
    }
    __syncthreads();
    if (tid < 16) {
        float v[32];
        float m = -1e30f;
#pragma unroll
        for (int c = 0; c < 32; ++c) { v[c] = slog[tid][c] + p.b_out[c]; m = fmaxf(m, v[c]); }
        float s = 0.f;
#pragma unroll
        for (int c = 0; c < 32; ++c) { v[c] = expf(v[c] - m); s += v[c]; }
        const float inv = 1.f / s;
        float* yp = p.y + ((size_t)(b0 + tid) * T_ + ty) * C_;
#pragma unroll
        for (int c = 0; c < 32; ++c) yp[c] = v[c] * inv;
    }
}

// ---------- persistent kernel: layer-pipelined T-loop ----------
// tick u: layer L computes t = u - L; out-proj computes t = u - 3.
__global__ __launch_bounds__(256) void gru_pipe(Params p) {
    __shared__ u16 hs[4][8192];          // staged h: [hp_hi, hp_lo, hin_hi, hin_lo], 64KB
    __shared__ float sg[6][16][33];
    __shared__ float slog[16][33];
    const int wg = blockIdx.x, tid = threadIdx.x;
    for (int u = 0; u < NT; ++u) {
        if (wg < NWG_CELL) {
            const int L = wg >> 6, wgl = wg & 63;
            const int t = u - L;
            if (t >= 0 && t < T_) {
                const int rs = t & 1, wsl = rs ^ 1;
                if (L == 0)      cell_phase<0>(p, t, rs, wsl, wgl, tid, sg, hs);
                else if (L == 1) cell_phase<1>(p, t, rs, wsl, wgl, tid, sg, hs);
                else             cell_phase<2>(p, t, rs, wsl, wgl, tid, sg, hs);
            }
        } else {
            const int t = u - 3;
            if (t >= 0) outproj_phase(p, t, (t + 1) & 1, wg, tid, slog, hs);
        }
        grid_barrier(p.bar, wg, tid, (u32)u);
    }
}

extern "C" void kernel_launch(void* const* d_in, const int* in_sizes, int n_in,
                              void* d_out, int out_size, void* d_ws, size_t ws_size,
                              hipStream_t stream) {
    (void)in_sizes; (void)n_in; (void)out_size; (void)ws_size;

    const float* x      = (const float*)d_in[0];
    const float* h0[3]  = {(const float*)d_in[1], (const float*)d_in[2], (const float*)d_in[3]};
    const float* Wih[3] = {(const float*)d_in[4], (const float*)d_in[8], (const float*)d_in[12]};
    const float* Whh[3] = {(const float*)d_in[5], (const float*)d_in[9], (const float*)d_in[13]};
    const float* bih[3] = {(const float*)d_in[6], (const float*)d_in[10], (const float*)d_in[14]};
    const float* bhh[3] = {(const float*)d_in[7], (const float*)d_in[11], (const float*)d_in[15]};
    const float* Wout   = (const float*)d_in[16];
    const float* bout   = (const float*)d_in[17];

    // ---- ws layout (u16 units): split-bf16 planes for weights + h state + barrier ----
    u16* w = (u16*)d_ws;
    size_t off = 0;
    auto take = [&](size_t n) { u16* p = w + off; off += n; return p; };
    u16 *ihh[3], *ihl[3], *hhh[3], *hhl[3];
    const size_t szih[3] = {(size_t)3 * H_ * IN_, (size_t)3 * H_ * H_, (size_t)3 * H_ * H_};
    const size_t szhh = (size_t)3 * H_ * H_;
    for (int l = 0; l < 3; ++l) {
        ihh[l] = take(szih[l]); ihl[l] = take(szih[l]);
        hhh[l] = take(szhh);    hhl[l] = take(szhh);
    }
    u16* wouth = take((size_t)C_ * H_);
    u16* woutl = take((size_t)C_ * H_);
    u16* hhi = take((size_t)3 * 2 * BH_);
    u16* hlo = take((size_t)3 * 2 * BH_);
    off = (off + 255) & ~(size_t)255;               // align barrier to 512B
    u32* bar = (u32*)take(2 * ((NGRP + 2) * 32));
    const size_t bar_bytes = (size_t)(NGRP + 2) * 32 * sizeof(u32);

    hipMemsetAsync(bar, 0, bar_bytes, stream);      // reset barrier every launch (graph-safe)

    auto split = [&](const float* src, u16* hi, u16* lo, int n) {
        split_kernel<<<dim3((n + 255) / 256), dim3(256), 0, stream>>>(src, hi, lo, n);
    };
    for (int l = 0; l < 3; ++l) {
        split(Wih[l], ihh[l], ihl[l], (int)szih[l]);
        split(Whh[l], hhh[l], hhl[l], (int)szhh);
    }
    split(Wout, wouth, woutl, C_ * H_);
    for (int l = 0; l < 3; ++l)   // h0 -> slot 0 of each layer
        split(h0[l], hhi + (size_t)(2 * l) * BH_, hlo + (size_t)(2 * l) * BH_, BH_);

    Params p;
    p.x = x;
    for (int l = 0; l < 3; ++l) {
        p.ih_hi[l] = ihh[l]; p.ih_lo[l] = ihl[l];
        p.hh_hi[l] = hhh[l]; p.hh_lo[l] = hhl[l];
        p.b_ih[l] = bih[l];  p.b_hh[l] = bhh[l];
    }
    p.wout_hi = wouth; p.wout_lo = woutl; p.b_out = bout;
    p.h_hi = hhi; p.h_lo = hlo;
    p.bar = bar;
    p.y = (float*)d_out;

    void* args[] = {&p};
    hipError_t err = hipLaunchCooperativeKernel((void*)gru_pipe, dim3(NWG_TOT), dim3(256),
                                                args, 0u, stream);
    if (err != hipSuccess) {
        // 196 blocks trivially co-reside on 256 CUs; the custom barrier needs
        // only co-residency, not cooperative semantics.
        gru_pipe<<<dim3(NWG_TOT), dim3(256), 0, stream>>>(p);
    }
}

// Round 5
// 3423.887 us; speedup vs baseline: 17.7157x; 2.2272x over previous
//
#include <hip/hip_runtime.h>

typedef unsigned short u16;
typedef unsigned int u32;
typedef unsigned long long u64;
typedef __attribute__((ext_vector_type(8))) short bf16x8;   // 8 bf16 in 4 VGPRs
typedef __attribute__((ext_vector_type(4))) float f32x4;

#define T_ 512
#define B_ 64
#define IN_ 128
#define H_ 512
#define C_ 32
#define BH_ (B_ * H_)        // 32768 elems per h plane
#define NWG_LAYER 64         // cell WGs per layer (each owns 32u x 16b)
#define NWG_CELL 192         // 3 layers x 64
#define NWG_TOT 196          // + 4 out-proj WGs  (<=256: coop launch validates)
#define NGRP 7               // ceil(196/32) arrive-counter groups
#define NT 515               // T + 3 pipeline ticks

#define DEVINL __device__ __attribute__((always_inline)) inline

// ---------- bf16 split helpers (RNE) ----------
DEVINL u16 f2bf_(float f) {
    u32 u = __float_as_uint(f);
    u32 r = (u + 0x7FFFu + ((u >> 16) & 1u)) >> 16;
    return (u16)r;
}
DEVINL float bf2f_(u16 h) { return __uint_as_float(((u32)h) << 16); }

// ---------- LLC-direct (agent-scope, relaxed) access for h exchange ----------
DEVINL u64 ld_llc_u64(const u64* p) {
    return __hip_atomic_load((u64*)p, __ATOMIC_RELAXED, __HIP_MEMORY_SCOPE_AGENT);
}
DEVINL void st_llc_u32(u32* p, u32 v) {
    __hip_atomic_store(p, v, __ATOMIC_RELAXED, __HIP_MEMORY_SCOPE_AGENT);
}

// ---------- weight / h0 split kernel: fp32 -> (hi, lo) bf16 planes ----------
__global__ void split_kernel(const float* __restrict__ src, u16* __restrict__ hi,
                             u16* __restrict__ lo, int n) {
    int i = blockIdx.x * 256 + threadIdx.x;
    if (i < n) {
        float f = src[i];
        u16 h = f2bf_(f);
        hi[i] = h;
        lo[i] = f2bf_(f - bf2f_(h));
    }
}

// ---------- params ----------
struct Params {
    const float* x;
    const u16* ih_hi[3]; const u16* ih_lo[3];
    const u16* hh_hi[3]; const u16* hh_lo[3];
    const float* b_ih[3]; const float* b_hh[3];
    const u16* wout_hi; const u16* wout_lo;
    const float* b_out;
    u16* h_hi; u16* h_lo;   // [3 layers][2 slots][B*H]
    u32* bar;               // barrier state (zeroed per launch)
    float* y;               // [B][T][C]
};

// ---------- fully-relaxed hierarchical grid barrier (R4-validated) ----------
DEVINL void grid_barrier(u32* bar, int wg, int tid, u32 tick) {
    __syncthreads();
    if (tid == 0) {
        const int g = wg >> 5;
        const u32 gsz = (g == NGRP - 1) ? (u32)(NWG_TOT - 32 * (NGRP - 1)) : 32u;
        u32 old = __hip_atomic_fetch_add(&bar[g * 32], 1u,
                                         __ATOMIC_RELAXED, __HIP_MEMORY_SCOPE_AGENT);
        if (old == (tick + 1u) * gsz - 1u) {           // last of this group this tick
            u32 o2 = __hip_atomic_fetch_add(&bar[NGRP * 32], 1u,
                                            __ATOMIC_RELAXED, __HIP_MEMORY_SCOPE_AGENT);
            if (o2 == (tick + 1u) * (u32)NGRP - 1u)    // last group overall
                __hip_atomic_store(&bar[NGRP * 32 + 32], tick + 1u,
                                   __ATOMIC_RELAXED, __HIP_MEMORY_SCOPE_AGENT);
        }
        while (__hip_atomic_load(&bar[NGRP * 32 + 32],
                                 __ATOMIC_RELAXED, __HIP_MEMORY_SCOPE_AGENT) < tick + 1u) {
            __builtin_amdgcn_s_sleep(1);
        }
    }
    __syncthreads();
}

// ---------- MFMA helpers ----------
DEVINL bf16x8 ld8(const u16* p) { return *reinterpret_cast<const bf16x8*>(p); }

// staged-h LDS read: [16][512] u16 rows, byte ^= (row&7)<<4 swizzle
DEVINL bf16x8 ld8_lds(const u16* s, int row, int kb) {
    const int bo = (row << 10) + (((kb) << 1) ^ ((row & 7) << 4));
    return *reinterpret_cast<const bf16x8*>((const char*)s + bo);
}

DEVINL f32x4 mfma3(bf16x8 ah, bf16x8 al, bf16x8 bh, bf16x8 bl, f32x4 c) {
    c = __builtin_amdgcn_mfma_f32_16x16x32_bf16(ah, bh, c, 0, 0, 0);
    c = __builtin_amdgcn_mfma_f32_16x16x32_bf16(al, bh, c, 0, 0, 0);
    c = __builtin_amdgcn_mfma_f32_16x16x32_bf16(ah, bl, c, 0, 0, 0);
    return c;
}

// A from staged LDS (row = ln15), B from pinned registers
DEVINL void gemm3_reg(const u16* sAh, const u16* sAl, int row,
                      const bf16x8 (&w)[3][2][16], int lhi,
                      f32x4& o0, f32x4& o1, f32x4& o2) {
    f32x4 a0 = {0.f,0.f,0.f,0.f}, a1 = {0.f,0.f,0.f,0.f}, a2 = {0.f,0.f,0.f,0.f};
#pragma unroll
    for (int kt = 0; kt < 16; ++kt) {
        const int kb = kt * 32 + lhi * 8;
        bf16x8 ah = ld8_lds(sAh, row, kb), al = ld8_lds(sAl, row, kb);
        a0 = mfma3(ah, al, w[0][0][kt], w[0][1][kt], a0);
        a1 = mfma3(ah, al, w[1][0][kt], w[1][1][kt], a1);
        a2 = mfma3(ah, al, w[2][0][kt], w[2][1][kt], a2);
    }
    o0 = a0; o1 = a1; o2 = a2;
}

DEVINL void gemm2_reg(const u16* sAh, const u16* sAl, int row,
                      const bf16x8 (&w)[3][2][16], int lhi,
                      f32x4& o0, f32x4& o1) {
    f32x4 a0 = {0.f,0.f,0.f,0.f}, a1 = {0.f,0.f,0.f,0.f};
#pragma unroll
    for (int kt = 0; kt < 16; ++kt) {
        const int kb = kt * 32 + lhi * 8;
        bf16x8 ah = ld8_lds(sAh, row, kb), al = ld8_lds(sAl, row, kb);
        a0 = mfma3(ah, al, w[0][0][kt], w[0][1][kt], a0);
        a1 = mfma3(ah, al, w[1][0][kt], w[1][1][kt], a1);
    }
    o0 = a0; o1 = a1;
}

// ---------- stage one h block (16 rows x 512, hi+lo) LLC->LDS, 2 chunks ----------
DEVINL void stage_h(const u16* ghi, const u16* glo,
                    u16* shi, u16* slo, int b0, int tid) {
#pragma unroll
    for (int c = 0; c < 2; ++c) {
        u64 rh[4], rl[4];
#pragma unroll
        for (int k = 0; k < 4; ++k) {
            const int idx = tid + ((c * 4 + k) << 8);
            const int row = idx >> 7, col = idx & 127;   // 128 u64 per 512-u16 row
            rh[k] = ld_llc_u64((const u64*)(ghi + (size_t)(b0 + row) * H_) + col);
            rl[k] = ld_llc_u64((const u64*)(glo + (size_t)(b0 + row) * H_) + col);
        }
#pragma unroll
        for (int k = 0; k < 4; ++k) {
            const int idx = tid + ((c * 4 + k) << 8);
            const int row = idx >> 7;
            const int so = (row << 10) + (((idx & 127) << 3) ^ ((row & 7) << 4));
            *(u64*)((char*)shi + so) = rh[k];
            *(u64*)((char*)slo + so) = rl[k];
        }
    }
}

// C/D layout (m89-verified): col = lane&15, row = (lane>>4)*4 + reg
DEVINL void store_sg(float (&dst)[16][33], f32x4 a, int col, int lhi) {
#pragma unroll
    for (int q = 0; q < 4; ++q) dst[lhi * 4 + q][col] = a[q];
}

// ---------- persistent kernel: layer-pipelined T-loop, weights pinned in VGPRs ----------
// tick u: layer L computes t = u - L; out-proj computes t = u - 3.
__global__ __launch_bounds__(256, 1) void gru_pipe(Params p) {
    __shared__ u16 hs[4][8192];          // staged h: [hp_hi, hp_lo, hin_hi, hin_lo], 64KB
    __shared__ float sg[6][16][33];
    __shared__ float slog[16][33];
    const int wg = blockIdx.x, tid = threadIdx.x;
    const int wave = tid >> 6, lane = tid & 63;
    const int ln15 = lane & 15, lhi = lane >> 4;

    // ---- prologue: pin this wave's weight tiles in registers ----
    // cell WG: 3 tiles (tt = wave*3+j), gate g = tt>>1, col c = (tt&1)*16 + ln15.
    //   waves 0-1: gi gates (W_ih), waves 2-3: gh gates (W_hh).
    // out-proj WG (wave 0): 2 tiles = W_out rows ln15, 16+ln15.
    bf16x8 wreg[3][2][16];
    const int L = (wg < NWG_CELL) ? (wg >> 6) : 0;
    const int wgl = wg & 63, ug = wgl & 15, mb = wgl >> 4;
    const int u0 = ug * 32, b0c = mb * 16;
    const int tt0 = wave * 3;
    if (wg < NWG_CELL) {
        if (wave >= 2) {
#pragma unroll
            for (int j = 0; j < 3; ++j) {
                const int tt = tt0 + j, g = (tt >> 1) - 3, c = (tt & 1) * 16 + ln15;
                const u16* bh = p.hh_hi[L] + (size_t)(g * H_ + u0 + c) * H_;
                const u16* bl = p.hh_lo[L] + (size_t)(g * H_ + u0 + c) * H_;
#pragma unroll
                for (int kt = 0; kt < 16; ++kt) {
                    wreg[j][0][kt] = ld8(bh + kt * 32 + lhi * 8);
                    wreg[j][1][kt] = ld8(bl + kt * 32 + lhi * 8);
                }
            }
        } else if (L > 0) {
#pragma unroll
            for (int j = 0; j < 3; ++j) {
                const int tt = tt0 + j, g = tt >> 1, c = (tt & 1) * 16 + ln15;
                const u16* bh = p.ih_hi[L] + (size_t)(g * H_ + u0 + c) * H_;
                const u16* bl = p.ih_lo[L] + (size_t)(g * H_ + u0 + c) * H_;
#pragma unroll
                for (int kt = 0; kt < 16; ++kt) {
                    wreg[j][0][kt] = ld8(bh + kt * 32 + lhi * 8);
                    wreg[j][1][kt] = ld8(bl + kt * 32 + lhi * 8);
                }
            }
        } else {
            // L0 gi: K = IN_ = 128 -> only 4 K-slices
#pragma unroll
            for (int j = 0; j < 3; ++j) {
                const int tt = tt0 + j, g = tt >> 1, c = (tt & 1) * 16 + ln15;
                const u16* bh = p.ih_hi[0] + (size_t)(g * H_ + u0 + c) * IN_;
                const u16* bl = p.ih_lo[0] + (size_t)(g * H_ + u0 + c) * IN_;
#pragma unroll
                for (int kt = 0; kt < 4; ++kt) {
                    wreg[j][0][kt] = ld8(bh + kt * 32 + lhi * 8);
                    wreg[j][1][kt] = ld8(bl + kt * 32 + lhi * 8);
                }
            }
        }
    } else if (wave == 0) {
#pragma unroll
        for (int j = 0; j < 2; ++j) {
            const u16* bh = p.wout_hi + (size_t)(j * 16 + ln15) * H_;
            const u16* bl = p.wout_lo + (size_t)(j * 16 + ln15) * H_;
#pragma unroll
            for (int kt = 0; kt < 16; ++kt) {
                wreg[j][0][kt] = ld8(bh + kt * 32 + lhi * 8);
                wreg[j][1][kt] = ld8(bl + kt * 32 + lhi * 8);
            }
        }
    }

    // ---- main loop ----
    for (int u = 0; u < NT; ++u) {
        if (wg < NWG_CELL) {
            const int t = u - L;
            if (t >= 0 && t < T_) {
                const int rs = t & 1, wsl = rs ^ 1;
                const u16* hp_hi = p.h_hi + (size_t)(2 * L + rs) * BH_;   // h_own(t-1)
                const u16* hp_lo = p.h_lo + (size_t)(2 * L + rs) * BH_;
                // stage h via LLC into LDS
                stage_h(hp_hi, hp_lo, hs[0], hs[1], b0c, tid);
                if (L > 0) {
                    const u16* hi_hi = p.h_hi + (size_t)(2 * (L - 1) + wsl) * BH_;  // h_{L-1}(t)
                    const u16* hi_lo = p.h_lo + (size_t)(2 * (L - 1) + wsl) * BH_;
                    stage_h(hi_hi, hi_lo, hs[2], hs[3], b0c, tid);
                }
                __syncthreads();

                f32x4 oA, oB, oC;
                if (wave < 2 && L == 0) {
                    // A = x_t rows (cached loads), split on the fly; K = 128
                    const float* xr = p.x + (size_t)(b0c + ln15) * (T_ * IN_) + (size_t)t * IN_;
                    f32x4 a0 = {0.f,0.f,0.f,0.f}, a1 = {0.f,0.f,0.f,0.f}, a2 = {0.f,0.f,0.f,0.f};
#pragma unroll
                    for (int kt = 0; kt < 4; ++kt) {
                        const int kb = kt * 32 + lhi * 8;
                        bf16x8 ah, al;
#pragma unroll
                        for (int j = 0; j < 8; ++j) {
                            float f = xr[kb + j];
                            u16 hb = f2bf_(f);
                            ah[j] = (short)hb;
                            al[j] = (short)f2bf_(f - bf2f_(hb));
                        }
                        a0 = mfma3(ah, al, wreg[0][0][kt], wreg[0][1][kt], a0);
                        a1 = mfma3(ah, al, wreg[1][0][kt], wreg[1][1][kt], a1);
                        a2 = mfma3(ah, al, wreg[2][0][kt], wreg[2][1][kt], a2);
                    }
                    oA = a0; oB = a1; oC = a2;
                } else {
                    const u16* sAh = (wave < 2) ? hs[2] : hs[0];
                    const u16* sAl = (wave < 2) ? hs[3] : hs[1];
                    gemm3_reg(sAh, sAl, ln15, wreg, lhi, oA, oB, oC);
                }
                {
                    const int gA = (tt0    ) >> 1, cA = ((tt0    ) & 1) * 16 + ln15;
                    const int gB = (tt0 + 1) >> 1, cB = ((tt0 + 1) & 1) * 16 + ln15;
                    const int gC = (tt0 + 2) >> 1, cC = ((tt0 + 2) & 1) * 16 + ln15;
                    store_sg(sg[gA], oA, cA, lhi);
                    store_sg(sg[gB], oB, cB, lhi);
                    store_sg(sg[gC], oC, cC, lhi);
                }
                __syncthreads();

                // ---- elementwise GRU update (fp32): 2 consecutive u per thread ----
                {
                    const int rb = tid & 15, uu = tid >> 4;
                    const int colu = uu * 2;
                    const int gcol = u0 + colu;
                    const int bo = (colu * 2 + ((u0 & 511) * 2)) ^ ((rb & 7) << 4); // = gcol*2 ^ swz
                    const u32 hp2h = *(const u32*)((const char*)hs[0] + (rb << 10) + ((gcol * 2) ^ ((rb & 7) << 4)));
                    const u32 hp2l = *(const u32*)((const char*)hs[1] + (rb << 10) + ((gcol * 2) ^ ((rb & 7) << 4)));
                    (void)bo;
                    u32 packh = 0, packl = 0;
#pragma unroll
                    for (int half = 0; half < 2; ++half) {
                        const int uc = colu + half;
                        const int uidx = u0 + uc;
                        const float ir  = sg[0][rb][uc] + p.b_ih[L][uidx];
                        const float iz  = sg[1][rb][uc] + p.b_ih[L][H_ + uidx];
                        const float in_ = sg[2][rb][uc] + p.b_ih[L][2 * H_ + uidx];
                        const float hr  = sg[3][rb][uc] + p.b_hh[L][uidx];
                        const float hz  = sg[4][rb][uc] + p.b_hh[L][H_ + uidx];
                        const float hn  = sg[5][rb][uc] + p.b_hh[L][2 * H_ + uidx];
                        const float r = 1.f / (1.f + expf(-(ir + hr)));
                        const float z = 1.f / (1.f + expf(-(iz + hz)));
                        const float n = tanhf(in_ + r * hn);
                        const float hprev = bf2f_((u16)((half ? (hp2h >> 16) : hp2h) & 0xffffu))
                                          + bf2f_((u16)((half ? (hp2l >> 16) : hp2l) & 0xffffu));
                        const float hnew = (1.f - z) * n + z * hprev;
                        const u16 nh = f2bf_(hnew);
                        const u16 nl = f2bf_(hnew - bf2f_(nh));
                        packh |= (u32)nh << (16 * half);
                        packl |= (u32)nl << (16 * half);
                    }
                    u16* ho_hi = p.h_hi + (size_t)(2 * L + wsl) * BH_;
                    u16* ho_lo = p.h_lo + (size_t)(2 * L + wsl) * BH_;
                    const size_t hx = (size_t)(b0c + rb) * H_ + gcol;
                    st_llc_u32((u32*)(ho_hi + hx), packh);      // write-through to LLC
                    st_llc_u32((u32*)(ho_lo + hx), packl);
                }
            }
        } else {
            const int t = u - 3;
            if (t >= 0) {
                const int slot = (t + 1) & 1;
                const int b0 = (wg - NWG_CELL) * 16;
                const u16* Ah = p.h_hi + (size_t)(4 + slot) * BH_;   // h3(t)
                const u16* Al = p.h_lo + (size_t)(4 + slot) * BH_;
                stage_h(Ah, Al, hs[0], hs[1], b0, tid);
                __syncthreads();
                if (wave == 0) {
                    f32x4 a0, a1;
                    gemm2_reg(hs[0], hs[1], ln15, wreg, lhi, a0, a1);
#pragma unroll
                    for (int q = 0; q < 4; ++q) {
                        slog[lhi * 4 + q][ln15] = a0[q];
                        slog[lhi * 4 + q][16 + ln15] = a1[q];
                    }
                }
                __syncthreads();
                if (tid < 16) {
                    float v[32];
                    float m = -1e30f;
#pragma unroll
                    for (int c = 0; c < 32; ++c) { v[c] = slog[tid][c] + p.b_out[c]; m = fmaxf(m, v[c]); }
                    float s = 0.f;
#pragma unroll
                    for (int c = 0; c < 32; ++c) { v[c] = expf(v[c] - m); s += v[c]; }
                    const float inv = 1.f / s;
                    float* yp = p.y + ((size_t)(b0 + tid) * T_ + t) * C_;
#pragma unroll
                    for (int c = 0; c < 32; ++c) yp[c] = v[c] * inv;
                }
            }
        }
        grid_barrier(p.bar, wg, tid, (u32)u);
    }
}

extern "C" void kernel_launch(void* const* d_in, const int* in_sizes, int n_in,
                              void* d_out, int out_size, void* d_ws, size_t ws_size,
                              hipStream_t stream) {
    (void)in_sizes; (void)n_in; (void)out_size; (void)ws_size;

    const float* x      = (const float*)d_in[0];
    const float* h0[3]  = {(const float*)d_in[1], (const float*)d_in[2], (const float*)d_in[3]};
    const float* Wih[3] = {(const float*)d_in[4], (const float*)d_in[8], (const float*)d_in[12]};
    const float* Whh[3] = {(const float*)d_in[5], (const float*)d_in[9], (const float*)d_in[13]};
    const float* bih[3] = {(const float*)d_in[6], (const float*)d_in[10], (const float*)d_in[14]};
    const float* bhh[3] = {(const float*)d_in[7], (const float*)d_in[11], (const float*)d_in[15]};
    const float* Wout   = (const float*)d_in[16];
    const float* bout   = (const float*)d_in[17];

    // ---- ws layout (u16 units): split-bf16 planes for weights + h state + barrier ----
    u16* w = (u16*)d_ws;
    size_t off = 0;
    auto take = [&](size_t n) { u16* p = w + off; off += n; return p; };
    u16 *ihh[3], *ihl[3], *hhh[3], *hhl[3];
    const size_t szih[3] = {(size_t)3 * H_ * IN_, (size_t)3 * H_ * H_, (size_t)3 * H_ * H_};
    const size_t szhh = (size_t)3 * H_ * H_;
    for (int l = 0; l < 3; ++l) {
        ihh[l] = take(szih[l]); ihl[l] = take(szih[l]);
        hhh[l] = take(szhh);    hhl[l] = take(szhh);
    }
    u16* wouth = take((size_t)C_ * H_);
    u16* woutl = take((size_t)C_ * H_);
    u16* hhi = take((size_t)3 * 2 * BH_);
    u16* hlo = take((size_t)3 * 2 * BH_);
    off = (off + 255) & ~(size_t)255;               // align barrier to 512B
    u32* bar = (u32*)take(2 * ((NGRP + 2) * 32));
    const size_t bar_bytes = (size_t)(NGRP + 2) * 32 * sizeof(u32);

    hipMemsetAsync(bar, 0, bar_bytes, stream);      // reset barrier every launch (graph-safe)

    auto split = [&](const float* src, u16* hi, u16* lo, int n) {
        split_kernel<<<dim3((n + 255) / 256), dim3(256), 0, stream>>>(src, hi, lo, n);
    };
    for (int l = 0; l < 3; ++l) {
        split(Wih[l], ihh[l], ihl[l], (int)szih[l]);
        split(Whh[l], hhh[l], hhl[l], (int)szhh);
    }
    split(Wout, wouth, woutl, C_ * H_);
    for (int l = 0; l < 3; ++l)   // h0 -> slot 0 of each layer
        split(h0[l], hhi + (size_t)(2 * l) * BH_, hlo + (size_t)(2 * l) * BH_, BH_);

    Params p;
    p.x = x;
    for (int l = 0; l < 3; ++l) {
        p.ih_hi[l] = ihh[l]; p.ih_lo[l] = ihl[l];
        p.hh_hi[l] = hhh[l]; p.hh_lo[l] = hhl[l];
        p.b_ih[l] = bih[l];  p.b_hh[l] = bhh[l];
    }
    p.wout_hi = wouth; p.wout_lo = woutl; p.b_out = bout;
    p.h_hi = hhi; p.h_lo = hlo;
    p.bar = bar;
    p.y = (float*)d_out;

    void* args[] = {&p};
    hipError_t err = hipLaunchCooperativeKernel((void*)gru_pipe, dim3(NWG_TOT), dim3(256),
                                                args, 0u, stream);
    if (err != hipSuccess) {
        // 196 blocks trivially co-reside on 256 CUs; the custom barrier needs
        // only co-residency, not cooperative semantics.
        gru_pipe<<<dim3(NWG_TOT), dim3(256), 0, stream>>>(p);
    }
}

// Round 7
// 3250.858 us; speedup vs baseline: 18.6586x; 1.0532x over previous
//
#include <hip/hip_runtime.h>

typedef unsigned short u16;
typedef unsigned int u32;
typedef unsigned long long u64;
typedef __attribute__((ext_vector_type(8))) short bf16x8;   // 8 bf16 in 4 VGPRs
typedef __attribute__((ext_vector_type(4))) float f32x4;

#define T_ 512
#define B_ 64
#define IN_ 128
#define H_ 512
#define C_ 32
#define BH_ (B_ * H_)        // 32768 elems per h plane
#define NWG_CELL 192         // 3 layers x 64 (each WG owns 32u x 16b)
#define NWG_TOT 196          // + 4 out-proj WGs

// ---- flag indices (x32 u32 stride = 128B line separation) ----
// MIN-GATES (R6 bug fix): every 16-way condition is a generation word written
// by the LAST arriver of its group, never a raw sum compared against 16*t.
// acnt[L][mb]  : arrive counter for publish mini-barrier (internal)
// gen[L][mb]   : step generation; == t+1 when ALL 16 ug-WGs finished step t
// rack[Lm][mb][s], rgen[Lm][mb][s] : same pattern for layer Lm+1's input-stage
//                acks of slot s (round k = steps s, s+3, ... staged k times)
// fo[mb][s]    : outproj ack counter (single writer per word -> exact as-is)
#define FA(L, mb)       ((((L) * 4 + (mb))) * 32)
#define FG(L, mb)       (((12 + (L) * 4 + (mb))) * 32)
#define FRA(Lm, mb, s)  (((24 + ((Lm) * 4 + (mb)) * 3 + (s))) * 32)
#define FRG(Lm, mb, s)  (((48 + ((Lm) * 4 + (mb)) * 3 + (s))) * 32)
#define FO(mb, s)       (((72 + (mb) * 3 + (s))) * 32)
#define NFLAG 84

#define DEVINL __device__ __attribute__((always_inline)) inline

// ---------- bf16 split helpers (RNE) ----------
DEVINL u16 f2bf_(float f) {
    u32 u = __float_as_uint(f);
    u32 r = (u + 0x7FFFu + ((u >> 16) & 1u)) >> 16;
    return (u16)r;
}
DEVINL float bf2f_(u16 h) { return __uint_as_float(((u32)h) << 16); }

// ---------- LLC-direct (agent-scope, relaxed) ops ----------
DEVINL u64 ld_llc_u64(const u64* p) {
    return __hip_atomic_load((u64*)p, __ATOMIC_RELAXED, __HIP_MEMORY_SCOPE_AGENT);
}
DEVINL void st_llc_u32(u32* p, u32 v) {
    __hip_atomic_store(p, v, __ATOMIC_RELAXED, __HIP_MEMORY_SCOPE_AGENT);
}
DEVINL u32 ld_flag(u32* p) {
    return __hip_atomic_load(p, __ATOMIC_RELAXED, __HIP_MEMORY_SCOPE_AGENT);
}
DEVINL u32 add_flag(u32* p) {
    return __hip_atomic_fetch_add(p, 1u, __ATOMIC_RELAXED, __HIP_MEMORY_SCOPE_AGENT);
}
DEVINL void st_flag(u32* p, u32 v) {
    __hip_atomic_store(p, v, __ATOMIC_RELAXED, __HIP_MEMORY_SCOPE_AGENT);
}
DEVINL void wait_ge(u32* p, u32 v) {
    while (ld_flag(p) < v) __builtin_amdgcn_s_sleep(1);
}

// ---------- weight / h0 split kernel: fp32 -> (hi, lo) bf16 planes ----------
__global__ void split_kernel(const float* __restrict__ src, u16* __restrict__ hi,
                             u16* __restrict__ lo, int n) {
    int i = blockIdx.x * 256 + threadIdx.x;
    if (i < n) {
        float f = src[i];
        u16 h = f2bf_(f);
        hi[i] = h;
        lo[i] = f2bf_(f - bf2f_(h));
    }
}

// ---------- params ----------
struct Params {
    const float* x;
    const u16* ih_hi[3]; const u16* ih_lo[3];
    const u16* hh_hi[3]; const u16* hh_lo[3];
    const float* b_ih[3]; const float* b_hh[3];
    const u16* wout_hi; const u16* wout_lo;
    const float* b_out;
    u16* h_hi; u16* h_lo;   // [3 layers][3 slots][B*H]; h(t) in slot t%3, h0 in slot 2
    u32* bar;               // flag counters (zeroed per launch)
    float* y;               // [B][T][C]
};

// ---------- MFMA helpers ----------
DEVINL bf16x8 ld8(const u16* p) { return *reinterpret_cast<const bf16x8*>(p); }

// staged-h LDS read: [16][512] u16 rows, byte ^= (row&7)<<4 swizzle
DEVINL bf16x8 ld8_lds(const u16* s, int row, int kb) {
    const int bo = (row << 10) + (((kb) << 1) ^ ((row & 7) << 4));
    return *reinterpret_cast<const bf16x8*>((const char*)s + bo);
}

DEVINL f32x4 mfma3(bf16x8 ah, bf16x8 al, bf16x8 bh, bf16x8 bl, f32x4 c) {
    c = __builtin_amdgcn_mfma_f32_16x16x32_bf16(ah, bh, c, 0, 0, 0);
    c = __builtin_amdgcn_mfma_f32_16x16x32_bf16(al, bh, c, 0, 0, 0);
    c = __builtin_amdgcn_mfma_f32_16x16x32_bf16(ah, bl, c, 0, 0, 0);
    return c;
}

DEVINL void gemm3_reg(const u16* sAh, const u16* sAl, int row,
                      const bf16x8 (&w)[3][2][16], int lhi,
                      f32x4& o0, f32x4& o1, f32x4& o2) {
    f32x4 a0 = {0.f,0.f,0.f,0.f}, a1 = {0.f,0.f,0.f,0.f}, a2 = {0.f,0.f,0.f,0.f};
#pragma unroll
    for (int kt = 0; kt < 16; ++kt) {
        const int kb = kt * 32 + lhi * 8;
        bf16x8 ah = ld8_lds(sAh, row, kb), al = ld8_lds(sAl, row, kb);
        a0 = mfma3(ah, al, w[0][0][kt], w[0][1][kt], a0);
        a1 = mfma3(ah, al, w[1][0][kt], w[1][1][kt], a1);
        a2 = mfma3(ah, al, w[2][0][kt], w[2][1][kt], a2);
    }
    o0 = a0; o1 = a1; o2 = a2;
}

DEVINL void gemm2_reg(const u16* sAh, const u16* sAl, int row,
                      const bf16x8 (&w)[3][2][16], int lhi,
                      f32x4& o0, f32x4& o1) {
    f32x4 a0 = {0.f,0.f,0.f,0.f}, a1 = {0.f,0.f,0.f,0.f};
#pragma unroll
    for (int kt = 0; kt < 16; ++kt) {
        const int kb = kt * 32 + lhi * 8;
        bf16x8 ah = ld8_lds(sAh, row, kb), al = ld8_lds(sAl, row, kb);
        a0 = mfma3(ah, al, w[0][0][kt], w[0][1][kt], a0);
        a1 = mfma3(ah, al, w[1][0][kt], w[1][1][kt], a1);
    }
    o0 = a0; o1 = a1;
}

// ---------- stage one h block (16 rows x 512, hi+lo) LLC->LDS ----------
DEVINL void stage_h(const u16* ghi, const u16* glo,
                    u16* shi, u16* slo, int b0, int tid) {
#pragma unroll
    for (int c = 0; c < 2; ++c) {
        u64 rh[4], rl[4];
#pragma unroll
        for (int k = 0; k < 4; ++k) {
            const int idx = tid + ((c * 4 + k) << 8);
            const int row = idx >> 7, col = idx & 127;   // 128 u64 per 512-u16 row
            rh[k] = ld_llc_u64((const u64*)(ghi + (size_t)(b0 + row) * H_) + col);
            rl[k] = ld_llc_u64((const u64*)(glo + (size_t)(b0 + row) * H_) + col);
        }
#pragma unroll
        for (int k = 0; k < 4; ++k) {
            const int idx = tid + ((c * 4 + k) << 8);
            const int row = idx >> 7;
            const int so = (row << 10) + (((idx & 127) << 3) ^ ((row & 7) << 4));
            *(u64*)((char*)shi + so) = rh[k];
            *(u64*)((char*)slo + so) = rl[k];
        }
    }
}

// C/D layout (m89-verified): col = lane&15, row = (lane>>4)*4 + reg
DEVINL void store_sg(float (&dst)[16][33], f32x4 a, int col, int lhi) {
#pragma unroll
    for (int q = 0; q < 4; ++q) dst[lhi * 4 + q][col] = a[q];
}

// ---------- persistent kernel: point-to-point flag-synced T-loop ----------
// Each (L,mb) 16-WG group free-runs; triple-buffered h slots + min-gate
// generation words bound skew. Safety:
//  - own h(t-1) complete  <=> gen[L][mb] >= t   (min-gate: last arriver only)
//  - input h_{L-1}(t)     <=> gen[L-1][mb] >= t+1
//  - own-layer WAR on slot t%3 (h(t-3)): gen >= t implies ALL peers finished
//    step t-1, hence staged h(t-3) at their step t-2. (true with min-gate)
//  - cross-layer WAR: rgen[L][mb][s] >= k <=> ALL 16 readers staged round k.
//  - outproj WAR: fo[mb][s] is single-writer -> raw count exact.
//  - h0 (slot 2) overwritten at t=2: gen >= 2 covers peers' step-0 staging;
//    no cross reader ever reads h_L(-1).
// Arrival grouping: a WG cannot arrive for step t+1 before gen >= t+1 (its own
// gate), so acnt groups cleanly per step; same for rack via the writer's
// back-pressure chain.
__global__ __launch_bounds__(256, 1) void gru_pipe(Params p) {
    __shared__ u16 hs[4][8192];          // [own_hi, own_lo, in_hi, in_lo], 64KB
    __shared__ float sg[6][16][33];
    __shared__ float slog[16][33];
    const int wg = blockIdx.x, tid = threadIdx.x;
    const int wave = tid >> 6, lane = tid & 63;
    const int ln15 = lane & 15, lhi = lane >> 4;
    u32* F = p.bar;

    // ---- prologue: pin this wave's weight tiles in registers (VGPR+AGPR) ----
    bf16x8 wreg[3][2][16];
    const int L = (wg < NWG_CELL) ? (wg >> 6) : 0;
    const int wgl = wg & 63, ug = wgl & 15, mb = wgl >> 4;
    const int u0 = ug * 32, b0c = mb * 16;
    const int tt0 = wave * 3;
    (void)ug;
    if (wg < NWG_CELL) {
        if (wave >= 2) {
#pragma unroll
            for (int j = 0; j < 3; ++j) {
                const int tt = tt0 + j, g = (tt >> 1) - 3, c = (tt & 1) * 16 + ln15;
                const u16* bh = p.hh_hi[L] + (size_t)(g * H_ + u0 + c) * H_;
                const u16* bl = p.hh_lo[L] + (size_t)(g * H_ + u0 + c) * H_;
#pragma unroll
                for (int kt = 0; kt < 16; ++kt) {
                    wreg[j][0][kt] = ld8(bh + kt * 32 + lhi * 8);
                    wreg[j][1][kt] = ld8(bl + kt * 32 + lhi * 8);
                }
            }
        } else if (L > 0) {
#pragma unroll
            for (int j = 0; j < 3; ++j) {
                const int tt = tt0 + j, g = tt >> 1, c = (tt & 1) * 16 + ln15;
                const u16* bh = p.ih_hi[L] + (size_t)(g * H_ + u0 + c) * H_;
                const u16* bl = p.ih_lo[L] + (size_t)(g * H_ + u0 + c) * H_;
#pragma unroll
                for (int kt = 0; kt < 16; ++kt) {
                    wreg[j][0][kt] = ld8(bh + kt * 32 + lhi * 8);
                    wreg[j][1][kt] = ld8(bl + kt * 32 + lhi * 8);
                }
            }
        } else {
#pragma unroll
            for (int j = 0; j < 3; ++j) {
                const int tt = tt0 + j, g = tt >> 1, c = (tt & 1) * 16 + ln15;
                const u16* bh = p.ih_hi[0] + (size_t)(g * H_ + u0 + c) * IN_;
                const u16* bl = p.ih_lo[0] + (size_t)(g * H_ + u0 + c) * IN_;
#pragma unroll
                for (int kt = 0; kt < 4; ++kt) {
                    wreg[j][0][kt] = ld8(bh + kt * 32 + lhi * 8);
                    wreg[j][1][kt] = ld8(bl + kt * 32 + lhi * 8);
                }
            }
        }
    } else if (wave == 0) {
#pragma unroll
        for (int j = 0; j < 2; ++j) {
            const u16* bh = p.wout_hi + (size_t)(j * 16 + ln15) * H_;
            const u16* bl = p.wout_lo + (size_t)(j * 16 + ln15) * H_;
#pragma unroll
            for (int kt = 0; kt < 16; ++kt) {
                wreg[j][0][kt] = ld8(bh + kt * 32 + lhi * 8);
                wreg[j][1][kt] = ld8(bl + kt * 32 + lhi * 8);
            }
        }
    }

    if (wg < NWG_CELL) {
        for (int t = 0; t < T_; ++t) {
            const int sCur = t % 3, sPrev = (t + 2) % 3;
            if (tid == 0) {
                wait_ge(&F[FG(L, mb)], (u32)t);                     // own h(t-1) done (min-gate)
                if (L > 0) wait_ge(&F[FG(L - 1, mb)], (u32)(t + 1)); // input h(t) done (min-gate)
            }
            __syncthreads();
            stage_h(p.h_hi + (size_t)(3 * L + sPrev) * BH_,
                    p.h_lo + (size_t)(3 * L + sPrev) * BH_, hs[0], hs[1], b0c, tid);
            if (L > 0)
                stage_h(p.h_hi + (size_t)(3 * (L - 1) + sCur) * BH_,
                        p.h_lo + (size_t)(3 * (L - 1) + sCur) * BH_, hs[2], hs[3], b0c, tid);
            __syncthreads();
            if (tid == 0 && L > 0) {                 // ack input stage (min-gate publish)
                const u32 k = (u32)(t / 3) + 1u;
                u32 old = add_flag(&F[FRA(L - 1, mb, sCur)]);
                if (old == 16u * k - 1u) st_flag(&F[FRG(L - 1, mb, sCur)], k);
            }

            f32x4 oA, oB, oC;
            if (wave < 2 && L == 0) {
                // A = x_t rows (cached loads), split on the fly; K = 128
                const float* xr = p.x + (size_t)(b0c + ln15) * (T_ * IN_) + (size_t)t * IN_;
                f32x4 a0 = {0.f,0.f,0.f,0.f}, a1 = {0.f,0.f,0.f,0.f}, a2 = {0.f,0.f,0.f,0.f};
#pragma unroll
                for (int kt = 0; kt < 4; ++kt) {
                    const int kb = kt * 32 + lhi * 8;
                    bf16x8 ah, al;
#pragma unroll
                    for (int j = 0; j < 8; ++j) {
                        float f = xr[kb + j];
                        u16 hb = f2bf_(f);
                        ah[j] = (short)hb;
                        al[j] = (short)f2bf_(f - bf2f_(hb));
                    }
                    a0 = mfma3(ah, al, wreg[0][0][kt], wreg[0][1][kt], a0);
                    a1 = mfma3(ah, al, wreg[1][0][kt], wreg[1][1][kt], a1);
                    a2 = mfma3(ah, al, wreg[2][0][kt], wreg[2][1][kt], a2);
                }
                oA = a0; oB = a1; oC = a2;
            } else {
                const u16* sAh = (wave < 2) ? hs[2] : hs[0];
                const u16* sAl = (wave < 2) ? hs[3] : hs[1];
                gemm3_reg(sAh, sAl, ln15, wreg, lhi, oA, oB, oC);
            }
            {
                const int gA = (tt0    ) >> 1, cA = ((tt0    ) & 1) * 16 + ln15;
                const int gB = (tt0 + 1) >> 1, cB = ((tt0 + 1) & 1) * 16 + ln15;
                const int gC = (tt0 + 2) >> 1, cC = ((tt0 + 2) & 1) * 16 + ln15;
                store_sg(sg[gA], oA, cA, lhi);
                store_sg(sg[gB], oB, cB, lhi);
                store_sg(sg[gC], oC, cC, lhi);
            }
            __syncthreads();
            if (tid == 0 && t >= 3) {
                // WAR back-pressure: slot sCur holds h(t-3); wait for its cross readers
                const u32 k = (u32)((t - 3) / 3) + 1u;
                if (L < 2) wait_ge(&F[FRG(L, mb, sCur)], k);   // min-gate
                else       wait_ge(&F[FO(mb, sCur)], k);       // single-writer count, exact
            }
            __syncthreads();

            // ---- elementwise GRU update (fp32): 2 consecutive u per thread ----
            {
                const int rb = tid & 15, uu = tid >> 4;
                const int colu = uu * 2;
                const int gcol = u0 + colu;
                const u32 hp2h = *(const u32*)((const char*)hs[0] + (rb << 10) + ((gcol * 2) ^ ((rb & 7) << 4)));
                const u32 hp2l = *(const u32*)((const char*)hs[1] + (rb << 10) + ((gcol * 2) ^ ((rb & 7) << 4)));
                u32 packh = 0, packl = 0;
#pragma unroll
                for (int half = 0; half < 2; ++half) {
                    const int uc = colu + half;
                    const int uidx = u0 + uc;
                    const float ir  = sg[0][rb][uc] + p.b_ih[L][uidx];
                    const float iz  = sg[1][rb][uc] + p.b_ih[L][H_ + uidx];
                    const float in_ = sg[2][rb][uc] + p.b_ih[L][2 * H_ + uidx];
                    const float hr  = sg[3][rb][uc] + p.b_hh[L][uidx];
                    const float hz  = sg[4][rb][uc] + p.b_hh[L][H_ + uidx];
                    const float hn  = sg[5][rb][uc] + p.b_hh[L][2 * H_ + uidx];
                    const float r = 1.f / (1.f + expf(-(ir + hr)));
                    const float z = 1.f / (1.f + expf(-(iz + hz)));
                    const float n = tanhf(in_ + r * hn);
                    const float hprev = bf2f_((u16)((half ? (hp2h >> 16) : hp2h) & 0xffffu))
                                      + bf2f_((u16)((half ? (hp2l >> 16) : hp2l) & 0xffffu));
                    const float hnew = (1.f - z) * n + z * hprev;
                    const u16 nh = f2bf_(hnew);
                    const u16 nl = f2bf_(hnew - bf2f_(nh));
                    packh |= (u32)nh << (16 * half);
                    packl |= (u32)nl << (16 * half);
                }
                u16* ho_hi = p.h_hi + (size_t)(3 * L + sCur) * BH_;
                u16* ho_lo = p.h_lo + (size_t)(3 * L + sCur) * BH_;
                const size_t hx = (size_t)(b0c + rb) * H_ + gcol;
                st_llc_u32((u32*)(ho_hi + hx), packh);      // write-through to LLC
                st_llc_u32((u32*)(ho_lo + hx), packl);
            }
            __syncthreads();                                 // drain h stores (vmcnt 0)
            if (tid == 0) {                                  // publish h(t) (min-gate)
                u32 old = add_flag(&F[FA(L, mb)]);
                if (old == 16u * (u32)(t + 1) - 1u) st_flag(&F[FG(L, mb)], (u32)(t + 1));
            }
        }
    } else {
        const int mbo = wg - NWG_CELL, b0 = mbo * 16;
        for (int t = 0; t < T_; ++t) {
            const int s = t % 3;
            if (tid == 0) wait_ge(&F[FG(2, mbo)], (u32)(t + 1));   // h3(t) done (min-gate)
            __syncthreads();
            stage_h(p.h_hi + (size_t)(6 + s) * BH_, p.h_lo + (size_t)(6 + s) * BH_,
                    hs[0], hs[1], b0, tid);
            __syncthreads();
            if (tid == 0) add_flag(&F[FO(mbo, s)]);          // ack h3(t) stage (exact count)
            if (wave == 0) {
                f32x4 a0, a1;
                gemm2_reg(hs[0], hs[1], ln15, wreg, lhi, a0, a1);
#pragma unroll
                for (int q = 0; q < 4; ++q) {
                    slog[lhi * 4 + q][ln15] = a0[q];
                    slog[lhi * 4 + q][16 + ln15] = a1[q];
                }
            }
            __syncthreads();
            if (tid < 16) {
                float v[32];
                float m = -1e30f;
#pragma unroll
                for (int c = 0; c < 32; ++c) { v[c] = slog[tid][c] + p.b_out[c]; m = fmaxf(m, v[c]); }
                float sden = 0.f;
#pragma unroll
                for (int c = 0; c < 32; ++c) { v[c] = expf(v[c] - m); sden += v[c]; }
                const float inv = 1.f / sden;
                float* yp = p.y + ((size_t)(b0 + tid) * T_ + t) * C_;
#pragma unroll
                for (int c = 0; c < 32; ++c) yp[c] = v[c] * inv;
            }
        }
    }
}

extern "C" void kernel_launch(void* const* d_in, const int* in_sizes, int n_in,
                              void* d_out, int out_size, void* d_ws, size_t ws_size,
                              hipStream_t stream) {
    (void)in_sizes; (void)n_in; (void)out_size; (void)ws_size;

    const float* x      = (const float*)d_in[0];
    const float* h0[3]  = {(const float*)d_in[1], (const float*)d_in[2], (const float*)d_in[3]};
    const float* Wih[3] = {(const float*)d_in[4], (const float*)d_in[8], (const float*)d_in[12]};
    const float* Whh[3] = {(const float*)d_in[5], (const float*)d_in[9], (const float*)d_in[13]};
    const float* bih[3] = {(const float*)d_in[6], (const float*)d_in[10], (const float*)d_in[14]};
    const float* bhh[3] = {(const float*)d_in[7], (const float*)d_in[11], (const float*)d_in[15]};
    const float* Wout   = (const float*)d_in[16];
    const float* bout   = (const float*)d_in[17];

    // ---- ws layout (u16 units): split-bf16 weights + 3-slot h state + flags ----
    u16* w = (u16*)d_ws;
    size_t off = 0;
    auto take = [&](size_t n) { u16* p = w + off; off += n; return p; };
    u16 *ihh[3], *ihl[3], *hhh[3], *hhl[3];
    const size_t szih[3] = {(size_t)3 * H_ * IN_, (size_t)3 * H_ * H_, (size_t)3 * H_ * H_};
    const size_t szhh = (size_t)3 * H_ * H_;
    for (int l = 0; l < 3; ++l) {
        ihh[l] = take(szih[l]); ihl[l] = take(szih[l]);
        hhh[l] = take(szhh);    hhl[l] = take(szhh);
    }
    u16* wouth = take((size_t)C_ * H_);
    u16* woutl = take((size_t)C_ * H_);
    u16* hhi = take((size_t)3 * 3 * BH_);
    u16* hlo = take((size_t)3 * 3 * BH_);
    off = (off + 255) & ~(size_t)255;               // align flags to 512B
    u32* bar = (u32*)take(2 * (NFLAG * 32));        // NFLAG*32 u32 words
    const size_t bar_bytes = (size_t)NFLAG * 32 * sizeof(u32);

    hipMemsetAsync(bar, 0, bar_bytes, stream);      // reset flags every launch (graph-safe)

    auto split = [&](const float* src, u16* hi, u16* lo, int n) {
        split_kernel<<<dim3((n + 255) / 256), dim3(256), 0, stream>>>(src, hi, lo, n);
    };
    for (int l = 0; l < 3; ++l) {
        split(Wih[l], ihh[l], ihl[l], (int)szih[l]);
        split(Whh[l], hhh[l], hhl[l], (int)szhh);
    }
    split(Wout, wouth, woutl, C_ * H_);
    for (int l = 0; l < 3; ++l)   // h0 = version -1 -> slot 2 of each layer
        split(h0[l], hhi + (size_t)(3 * l + 2) * BH_, hlo + (size_t)(3 * l + 2) * BH_, BH_);

    Params p;
    p.x = x;
    for (int l = 0; l < 3; ++l) {
        p.ih_hi[l] = ihh[l]; p.ih_lo[l] = ihl[l];
        p.hh_hi[l] = hhh[l]; p.hh_lo[l] = hhl[l];
        p.b_ih[l] = bih[l];  p.b_hh[l] = bhh[l];
    }
    p.wout_hi = wouth; p.wout_lo = woutl; p.b_out = bout;
    p.h_hi = hhi; p.h_lo = hlo;
    p.bar = bar;
    p.y = (float*)d_out;

    void* args[] = {&p};
    hipError_t err = hipLaunchCooperativeKernel((void*)gru_pipe, dim3(NWG_TOT), dim3(256),
                                                args, 0u, stream);
    if (err != hipSuccess) {
        // flags-only sync needs co-residency, not cooperative semantics;
        // 196 blocks trivially co-reside on 256 CUs.
        gru_pipe<<<dim3(NWG_TOT), dim3(256), 0, stream>>>(p);
    }
}

// Round 10
// 3029.866 us; speedup vs baseline: 20.0195x; 1.0729x over previous
//
#include <hip/hip_runtime.h>

typedef unsigned short u16;
typedef unsigned int u32;
typedef unsigned long long u64;
typedef __attribute__((ext_vector_type(8))) short bf16x8;   // 8 bf16 in 4 VGPRs
typedef __attribute__((ext_vector_type(4))) float f32x4;

#define T_ 512
#define B_ 64
#define IN_ 128
#define H_ 512
#define C_ 32
#define BH_ (B_ * H_)        // 32768 elems per h plane
#define NWG_CELL 192         // 3 layers x 64 (each WG owns 32u x 16b)
#define NWG_TOT 196          // + 4 out-proj WGs

// ---- flag indices (x32 u32 stride = 128B line separation) ----
// R7-VERIFIED protocol (do not alter publish mechanics — R8/R9 lesson):
// acnt[L][mb]  : arrive counter for publish mini-barrier (atomic fetch_add)
// gen[L][mb]   : step generation; == t+1 when ALL 16 ug-WGs finished step t
//                (stored by the LAST arriver only -> true min-gate)
// rack/rgen[Lm][mb][s] : same pattern for layer Lm+1's input-stage acks
// fo[mb][s]    : outproj ack counter (single writer per word -> exact count)
#define FA(L, mb)       ((((L) * 4 + (mb))) * 32)
#define FG(L, mb)       (((12 + (L) * 4 + (mb))) * 32)
#define FRA(Lm, mb, s)  (((24 + ((Lm) * 4 + (mb)) * 3 + (s))) * 32)
#define FRG(Lm, mb, s)  (((48 + ((Lm) * 4 + (mb)) * 3 + (s))) * 32)
#define FO(mb, s)       (((72 + (mb) * 3 + (s))) * 32)
#define NFLAG 84

#define DEVINL __device__ __attribute__((always_inline)) inline

// ---------- bf16 split helpers (RNE) ----------
DEVINL u16 f2bf_(float f) {
    u32 u = __float_as_uint(f);
    u32 r = (u + 0x7FFFu + ((u >> 16) & 1u)) >> 16;
    return (u16)r;
}
DEVINL float bf2f_(u16 h) { return __uint_as_float(((u32)h) << 16); }

// ---------- LLC-direct (agent-scope, relaxed) ops ----------
DEVINL u64 ld_llc_u64(const u64* p) {
    return __hip_atomic_load((u64*)p, __ATOMIC_RELAXED, __HIP_MEMORY_SCOPE_AGENT);
}
DEVINL void st_llc_u32(u32* p, u32 v) {
    __hip_atomic_store(p, v, __ATOMIC_RELAXED, __HIP_MEMORY_SCOPE_AGENT);
}
DEVINL u32 ld_flag(const u32* p) {
    return __hip_atomic_load((u32*)p, __ATOMIC_RELAXED, __HIP_MEMORY_SCOPE_AGENT);
}
DEVINL u32 add_flag(u32* p) {
    return __hip_atomic_fetch_add(p, 1u, __ATOMIC_RELAXED, __HIP_MEMORY_SCOPE_AGENT);
}
DEVINL void st_flag(u32* p, u32 v) {
    __hip_atomic_store(p, v, __ATOMIC_RELAXED, __HIP_MEMORY_SCOPE_AGENT);
}
DEVINL void wait_ge(u32* p, u32 v) {
    while (ld_flag(p) < v) __builtin_amdgcn_s_sleep(1);
}

// ---------- weight / h0 split kernel: fp32 -> (hi, lo) bf16 planes ----------
__global__ void split_kernel(const float* __restrict__ src, u16* __restrict__ hi,
                             u16* __restrict__ lo, int n) {
    int i = blockIdx.x * 256 + threadIdx.x;
    if (i < n) {
        float f = src[i];
        u16 h = f2bf_(f);
        hi[i] = h;
        lo[i] = f2bf_(f - bf2f_(h));
    }
}

// ---------- params ----------
struct Params {
    const float* x;
    const u16* ih_hi[3]; const u16* ih_lo[3];
    const u16* hh_hi[3]; const u16* hh_lo[3];
    const float* b_ih[3]; const float* b_hh[3];
    const u16* wout_hi; const u16* wout_lo;
    const float* b_out;
    u16* h_hi; u16* h_lo;   // [3 layers][3 slots][B*H]; h(t) in slot t%3, h0 in slot 2
    u32* bar;               // flag counters (zeroed per launch)
    float* y;               // [B][T][C]
};

// ---------- MFMA helpers ----------
DEVINL bf16x8 ld8(const u16* p) { return *reinterpret_cast<const bf16x8*>(p); }

// staged-h LDS read: [16][512] u16 rows, byte ^= (row&7)<<4 swizzle
DEVINL bf16x8 ld8_lds(const u16* s, int row, int kb) {
    const int bo = (row << 10) + (((kb) << 1) ^ ((row & 7) << 4));
    return *reinterpret_cast<const bf16x8*>((const char*)s + bo);
}

DEVINL f32x4 mfma3(bf16x8 ah, bf16x8 al, bf16x8 bh, bf16x8 bl, f32x4 c) {
    c = __builtin_amdgcn_mfma_f32_16x16x32_bf16(ah, bh, c, 0, 0, 0);
    c = __builtin_amdgcn_mfma_f32_16x16x32_bf16(al, bh, c, 0, 0, 0);
    c = __builtin_amdgcn_mfma_f32_16x16x32_bf16(ah, bl, c, 0, 0, 0);
    return c;
}

DEVINL void gemm3_reg(const u16* sAh, const u16* sAl, int row,
                      const bf16x8 (&w)[3][2][16], int lhi,
                      f32x4& o0, f32x4& o1, f32x4& o2) {
    f32x4 a0 = {0.f,0.f,0.f,0.f}, a1 = {0.f,0.f,0.f,0.f}, a2 = {0.f,0.f,0.f,0.f};
#pragma unroll
    for (int kt = 0; kt < 16; ++kt) {
        const int kb = kt * 32 + lhi * 8;
        bf16x8 ah = ld8_lds(sAh, row, kb), al = ld8_lds(sAl, row, kb);
        a0 = mfma3(ah, al, w[0][0][kt], w[0][1][kt], a0);
        a1 = mfma3(ah, al, w[1][0][kt], w[1][1][kt], a1);
        a2 = mfma3(ah, al, w[2][0][kt], w[2][1][kt], a2);
    }
    o0 = a0; o1 = a1; o2 = a2;
}

DEVINL void gemm2_reg(const u16* sAh, const u16* sAl, int row,
                      const bf16x8 (&w)[3][2][16], int lhi,
                      f32x4& o0, f32x4& o1) {
    f32x4 a0 = {0.f,0.f,0.f,0.f}, a1 = {0.f,0.f,0.f,0.f};
#pragma unroll
    for (int kt = 0; kt < 16; ++kt) {
        const int kb = kt * 32 + lhi * 8;
        bf16x8 ah = ld8_lds(sAh, row, kb), al = ld8_lds(sAl, row, kb);
        a0 = mfma3(ah, al, w[0][0][kt], w[0][1][kt], a0);
        a1 = mfma3(ah, al, w[1][0][kt], w[1][1][kt], a1);
    }
    o0 = a0; o1 = a1;
}

// ---------- stage one h block (16 rows x 512, hi+lo) LLC->LDS ----------
DEVINL void stage_h(const u16* ghi, const u16* glo,
                    u16* shi, u16* slo, int b0, int tid) {
#pragma unroll
    for (int c = 0; c < 2; ++c) {
        u64 rh[4], rl[4];
#pragma unroll
        for (int k = 0; k < 4; ++k) {
            const int idx = tid + ((c * 4 + k) << 8);
            const int row = idx >> 7, col = idx & 127;   // 128 u64 per 512-u16 row
            rh[k] = ld_llc_u64((const u64*)(ghi + (size_t)(b0 + row) * H_) + col);
            rl[k] = ld_llc_u64((const u64*)(glo + (size_t)(b0 + row) * H_) + col);
        }
#pragma unroll
        for (int k = 0; k < 4; ++k) {
            const int idx = tid + ((c * 4 + k) << 8);
            const int row = idx >> 7;
            const int so = (row << 10) + (((idx & 127) << 3) ^ ((row & 7) << 4));
            *(u64*)((char*)shi + so) = rh[k];
            *(u64*)((char*)slo + so) = rl[k];
        }
    }
}

// C/D layout (m89-verified): col = lane&15, row = (lane>>4)*4 + reg
DEVINL void store_sg(float (&dst)[16][33], f32x4 a, int col, int lhi) {
#pragma unroll
    for (int q = 0; q < 4; ++q) dst[lhi * 4 + q][col] = a[q];
}

// ---------- persistent kernel: R7-protocol, fused single-poll gate ----------
// Safety identical to R7 (passed, absmax 4.88e-4):
//  - own h(t-1) ready       <=> gen[L][mb]   >= t    (min-gate)
//  - input h_{L-1}(t) ready <=> gen[L-1][mb] >= t+1  (min-gate)
//  - cross-layer WAR: rgen[L][mb][sCur] >= (t-3)/3+1 ; outproj WAR: fo >= same.
//    Moved from mid-step to the step-START fused gate: the condition is a
//    monotonic counter and its producers don't depend on our step-t work
//    (no cycle), so checking earlier is still sufficient and deadlock-free.
//  - publish mechanics BYTE-IDENTICAL to R7 (fetch_add + last-arriver gen
//    store). R8/R9 lesson: plain-store publish has an unresolved HW-level
//    visibility race (in-flight h stores vs flag store); the RMW+gen chain's
//    extra LLC round-trips cover it. Do not change without isolated probe.
__global__ __launch_bounds__(256, 1) void gru_pipe(Params p) {
    __shared__ u16 hs[4][8192];          // [own_hi, own_lo, in_hi, in_lo], 64KB
    __shared__ float sg[6][16][33];
    __shared__ float slog[16][33];
    const int wg = blockIdx.x, tid = threadIdx.x;
    const int wave = tid >> 6, lane = tid & 63;
    const int ln15 = lane & 15, lhi = lane >> 4;
    u32* F = p.bar;

    // ---- prologue: pin this wave's weight tiles in registers (VGPR+AGPR) ----
    bf16x8 wreg[3][2][16];
    const int L = (wg < NWG_CELL) ? (wg >> 6) : 0;
    const int wgl = wg & 63, ug = wgl & 15, mb = wgl >> 4;
    const int u0 = ug * 32, b0c = mb * 16;
    const int tt0 = wave * 3;
    if (wg < NWG_CELL) {
        if (wave >= 2) {
#pragma unroll
            for (int j = 0; j < 3; ++j) {
                const int tt = tt0 + j, g = (tt >> 1) - 3, c = (tt & 1) * 16 + ln15;
                const u16* bh = p.hh_hi[L] + (size_t)(g * H_ + u0 + c) * H_;
                const u16* bl = p.hh_lo[L] + (size_t)(g * H_ + u0 + c) * H_;
#pragma unroll
                for (int kt = 0; kt < 16; ++kt) {
                    wreg[j][0][kt] = ld8(bh + kt * 32 + lhi * 8);
                    wreg[j][1][kt] = ld8(bl + kt * 32 + lhi * 8);
                }
            }
        } else if (L > 0) {
#pragma unroll
            for (int j = 0; j < 3; ++j) {
                const int tt = tt0 + j, g = tt >> 1, c = (tt & 1) * 16 + ln15;
                const u16* bh = p.ih_hi[L] + (size_t)(g * H_ + u0 + c) * H_;
                const u16* bl = p.ih_lo[L] + (size_t)(g * H_ + u0 + c) * H_;
#pragma unroll
                for (int kt = 0; kt < 16; ++kt) {
                    wreg[j][0][kt] = ld8(bh + kt * 32 + lhi * 8);
                    wreg[j][1][kt] = ld8(bl + kt * 32 + lhi * 8);
                }
            }
        } else {
#pragma unroll
            for (int j = 0; j < 3; ++j) {
                const int tt = tt0 + j, g = tt >> 1, c = (tt & 1) * 16 + ln15;
                const u16* bh = p.ih_hi[0] + (size_t)(g * H_ + u0 + c) * IN_;
                const u16* bl = p.ih_lo[0] + (size_t)(g * H_ + u0 + c) * IN_;
#pragma unroll
                for (int kt = 0; kt < 4; ++kt) {
                    wreg[j][0][kt] = ld8(bh + kt * 32 + lhi * 8);
                    wreg[j][1][kt] = ld8(bl + kt * 32 + lhi * 8);
                }
            }
        }
    } else if (wave == 0) {
#pragma unroll
        for (int j = 0; j < 2; ++j) {
            const u16* bh = p.wout_hi + (size_t)(j * 16 + ln15) * H_;
            const u16* bl = p.wout_lo + (size_t)(j * 16 + ln15) * H_;
#pragma unroll
            for (int kt = 0; kt < 16; ++kt) {
                wreg[j][0][kt] = ld8(bh + kt * 32 + lhi * 8);
                wreg[j][1][kt] = ld8(bl + kt * 32 + lhi * 8);
            }
        }
    }

    if (wg < NWG_CELL) {
        for (int t = 0; t < T_; ++t) {
            const int sCur = t % 3, sPrev = (t + 2) % 3;
            // ---- FUSED gate: own + input + WAR in ONE poll loop (tid0) ----
            if (tid == 0) {
                u32* gO = &F[FG(L, mb)];
                const u32 thrO = (u32)t;
                u32* gI = (L > 0) ? &F[FG(L - 1, mb)] : gO;
                const u32 thrI = (L > 0) ? (u32)(t + 1) : 0u;
                u32* gW = gO; u32 thrW = 0u;
                if (t >= 3) {
                    thrW = (u32)((t - 3) / 3) + 1u;
                    gW = (L < 2) ? &F[FRG(L, mb, sCur)] : &F[FO(mb, sCur)];
                }
                // bitwise | : all three loads issue per iteration (no short-circuit)
                while ((u32)(ld_flag(gO) < thrO) | (u32)(ld_flag(gI) < thrI) |
                       (u32)(ld_flag(gW) < thrW)) {
                    __builtin_amdgcn_s_sleep(1);
                }
            }
            __syncthreads();                                 // #0: gate -> WG

            stage_h(p.h_hi + (size_t)(3 * L + sPrev) * BH_,
                    p.h_lo + (size_t)(3 * L + sPrev) * BH_, hs[0], hs[1], b0c, tid);
            if (L > 0)
                stage_h(p.h_hi + (size_t)(3 * (L - 1) + sCur) * BH_,
                        p.h_lo + (size_t)(3 * (L - 1) + sCur) * BH_, hs[2], hs[3], b0c, tid);
            __syncthreads();                                 // #1: stage visible WG-wide
            if (tid == 0 && L > 0) {                 // ack input stage (min-gate publish)
                const u32 k = (u32)(t / 3) + 1u;
                u32 old = add_flag(&F[FRA(L - 1, mb, sCur)]);
                if (old == 16u * k - 1u) st_flag(&F[FRG(L - 1, mb, sCur)], k);
            }

            f32x4 oA, oB, oC;
            if (wave < 2 && L == 0) {
                // A = x_t rows (cached loads), split on the fly; K = 128
                const float* xr = p.x + (size_t)(b0c + ln15) * (T_ * IN_) + (size_t)t * IN_;
                f32x4 a0 = {0.f,0.f,0.f,0.f}, a1 = {0.f,0.f,0.f,0.f}, a2 = {0.f,0.f,0.f,0.f};
#pragma unroll
                for (int kt = 0; kt < 4; ++kt) {
                    const int kb = kt * 32 + lhi * 8;
                    bf16x8 ah, al;
#pragma unroll
                    for (int j = 0; j < 8; ++j) {
                        float f = xr[kb + j];
                        u16 hb = f2bf_(f);
                        ah[j] = (short)hb;
                        al[j] = (short)f2bf_(f - bf2f_(hb));
                    }
                    a0 = mfma3(ah, al, wreg[0][0][kt], wreg[0][1][kt], a0);
                    a1 = mfma3(ah, al, wreg[1][0][kt], wreg[1][1][kt], a1);
                    a2 = mfma3(ah, al, wreg[2][0][kt], wreg[2][1][kt], a2);
                }
                oA = a0; oB = a1; oC = a2;
            } else {
                const u16* sAh = (wave < 2) ? hs[2] : hs[0];
                const u16* sAl = (wave < 2) ? hs[3] : hs[1];
                gemm3_reg(sAh, sAl, ln15, wreg, lhi, oA, oB, oC);
            }
            {
                const int gA = (tt0    ) >> 1, cA = ((tt0    ) & 1) * 16 + ln15;
                const int gB = (tt0 + 1) >> 1, cB = ((tt0 + 1) & 1) * 16 + ln15;
                const int gC = (tt0 + 2) >> 1, cC = ((tt0 + 2) & 1) * 16 + ln15;
                store_sg(sg[gA], oA, cA, lhi);
                store_sg(sg[gB], oB, cB, lhi);
                store_sg(sg[gC], oC, cC, lhi);
            }
            __syncthreads();                                 // #2: sg visible WG-wide

            // ---- elementwise GRU update (fp32): 2 consecutive u per thread ----
            {
                const int rb = tid & 15, uu = tid >> 4;
                const int colu = uu * 2;
                const int gcol = u0 + colu;
                const u32 hp2h = *(const u32*)((const char*)hs[0] + (rb << 10) + ((gcol * 2) ^ ((rb & 7) << 4)));
                const u32 hp2l = *(const u32*)((const char*)hs[1] + (rb << 10) + ((gcol * 2) ^ ((rb & 7) << 4)));
                u32 packh = 0, packl = 0;
#pragma unroll
                for (int half = 0; half < 2; ++half) {
                    const int uc = colu + half;
                    const int uidx = u0 + uc;
                    const float ir  = sg[0][rb][uc] + p.b_ih[L][uidx];
                    const float iz  = sg[1][rb][uc] + p.b_ih[L][H_ + uidx];
                    const float in_ = sg[2][rb][uc] + p.b_ih[L][2 * H_ + uidx];
                    const float hr  = sg[3][rb][uc] + p.b_hh[L][uidx];
                    const float hz  = sg[4][rb][uc] + p.b_hh[L][H_ + uidx];
                    const float hn  = sg[5][rb][uc] + p.b_hh[L][2 * H_ + uidx];
                    const float r = 1.f / (1.f + expf(-(ir + hr)));
                    const float z = 1.f / (1.f + expf(-(iz + hz)));
                    const float n = tanhf(in_ + r * hn);
                    const float hprev = bf2f_((u16)((half ? (hp2h >> 16) : hp2h) & 0xffffu))
                                      + bf2f_((u16)((half ? (hp2l >> 16) : hp2l) & 0xffffu));
                    const float hnew = (1.f - z) * n + z * hprev;
                    const u16 nh = f2bf_(hnew);
                    const u16 nl = f2bf_(hnew - bf2f_(nh));
                    packh |= (u32)nh << (16 * half);
                    packl |= (u32)nl << (16 * half);
                }
                u16* ho_hi = p.h_hi + (size_t)(3 * L + sCur) * BH_;
                u16* ho_lo = p.h_lo + (size_t)(3 * L + sCur) * BH_;
                const size_t hx = (size_t)(b0c + rb) * H_ + gcol;
                st_llc_u32((u32*)(ho_hi + hx), packh);      // write-through to LLC
                st_llc_u32((u32*)(ho_lo + hx), packl);
            }
            __syncthreads();                                 // #3: drains vmcnt (h stores done)
            if (tid == 0) {                                  // publish h(t) (min-gate, R7 exact)
                u32 old = add_flag(&F[FA(L, mb)]);
                if (old == 16u * (u32)(t + 1) - 1u) st_flag(&F[FG(L, mb)], (u32)(t + 1));
            }
        }
    } else {
        const int mbo = wg - NWG_CELL, b0 = mbo * 16;
        for (int t = 0; t < T_; ++t) {
            const int s = t % 3;
            if (tid == 0) wait_ge(&F[FG(2, mbo)], (u32)(t + 1));   // h3(t) done (min-gate)
            __syncthreads();
            stage_h(p.h_hi + (size_t)(6 + s) * BH_, p.h_lo + (size_t)(6 + s) * BH_,
                    hs[0], hs[1], b0, tid);
            __syncthreads();
            if (tid == 0) add_flag(&F[FO(mbo, s)]);          // ack h3(t) stage (exact count)
            if (wave == 0) {
                f32x4 a0, a1;
                gemm2_reg(hs[0], hs[1], ln15, wreg, lhi, a0, a1);
#pragma unroll
                for (int q = 0; q < 4; ++q) {
                    slog[lhi * 4 + q][ln15] = a0[q];
                    slog[lhi * 4 + q][16 + ln15] = a1[q];
                }
            }
            __syncthreads();
            if (tid < 16) {
                float v[32];
                float m = -1e30f;
#pragma unroll
                for (int c = 0; c < 32; ++c) { v[c] = slog[tid][c] + p.b_out[c]; m = fmaxf(m, v[c]); }
                float sden = 0.f;
#pragma unroll
                for (int c = 0; c < 32; ++c) { v[c] = expf(v[c] - m); sden += v[c]; }
                const float inv = 1.f / sden;
                float* yp = p.y + ((size_t)(b0 + tid) * T_ + t) * C_;
#pragma unroll
                for (int c = 0; c < 32; ++c) yp[c] = v[c] * inv;
            }
        }
    }
}

extern "C" void kernel_launch(void* const* d_in, const int* in_sizes, int n_in,
                              void* d_out, int out_size, void* d_ws, size_t ws_size,
                              hipStream_t stream) {
    (void)in_sizes; (void)n_in; (void)out_size; (void)ws_size;

    const float* x      = (const float*)d_in[0];
    const float* h0[3]  = {(const float*)d_in[1], (const float*)d_in[2], (const float*)d_in[3]};
    const float* Wih[3] = {(const float*)d_in[4], (const float*)d_in[8], (const float*)d_in[12]};
    const float* Whh[3] = {(const float*)d_in[5], (const float*)d_in[9], (const float*)d_in[13]};
    const float* bih[3] = {(const float*)d_in[6], (const float*)d_in[10], (const float*)d_in[14]};
    const float* bhh[3] = {(const float*)d_in[7], (const float*)d_in[11], (const float*)d_in[15]};
    const float* Wout   = (const float*)d_in[16];
    const float* bout   = (const float*)d_in[17];

    // ---- ws layout (u16 units): split-bf16 weights + 3-slot h state + flags ----
    u16* w = (u16*)d_ws;
    size_t off = 0;
    auto take = [&](size_t n) { u16* p = w + off; off += n; return p; };
    u16 *ihh[3], *ihl[3], *hhh[3], *hhl[3];
    const size_t szih[3] = {(size_t)3 * H_ * IN_, (size_t)3 * H_ * H_, (size_t)3 * H_ * H_};
    const size_t szhh = (size_t)3 * H_ * H_;
    for (int l = 0; l < 3; ++l) {
        ihh[l] = take(szih[l]); ihl[l] = take(szih[l]);
        hhh[l] = take(szhh);    hhl[l] = take(szhh);
    }
    u16* wouth = take((size_t)C_ * H_);
    u16* woutl = take((size_t)C_ * H_);
    u16* hhi = take((size_t)3 * 3 * BH_);
    u16* hlo = take((size_t)3 * 3 * BH_);
    off = (off + 255) & ~(size_t)255;               // align flags to 512B
    u32* bar = (u32*)take(2 * (NFLAG * 32));        // NFLAG*32 u32 words
    const size_t bar_bytes = (size_t)NFLAG * 32 * sizeof(u32);

    hipMemsetAsync(bar, 0, bar_bytes, stream);      // reset flags every launch (graph-safe)

    auto split = [&](const float* src, u16* hi, u16* lo, int n) {
        split_kernel<<<dim3((n + 255) / 256), dim3(256), 0, stream>>>(src, hi, lo, n);
    };
    for (int l = 0; l < 3; ++l) {
        split(Wih[l], ihh[l], ihl[l], (int)szih[l]);
        split(Whh[l], hhh[l], hhl[l], (int)szhh);
    }
    split(Wout, wouth, woutl, C_ * H_);
    for (int l = 0; l < 3; ++l)   // h0 = version -1 -> slot 2 of each layer
        split(h0[l], hhi + (size_t)(3 * l + 2) * BH_, hlo + (size_t)(3 * l + 2) * BH_, BH_);

    Params p;
    p.x = x;
    for (int l = 0; l < 3; ++l) {
        p.ih_hi[l] = ihh[l]; p.ih_lo[l] = ihl[l];
        p.hh_hi[l] = hhh[l]; p.hh_lo[l] = hhl[l];
        p.b_ih[l] = bih[l];  p.b_hh[l] = bhh[l];
    }
    p.wout_hi = wouth; p.wout_lo = woutl; p.b_out = bout;
    p.h_hi = hhi; p.h_lo = hlo;
    p.bar = bar;
    p.y = (float*)d_out;

    void* args[] = {&p};
    hipError_t err = hipLaunchCooperativeKernel((void*)gru_pipe, dim3(NWG_TOT), dim3(256),
                                                args, 0u, stream);
    if (err != hipSuccess) {
        // flags-only sync needs co-residency, not cooperative semantics;
        // 196 blocks trivially co-reside on 256 CUs.
        gru_pipe<<<dim3(NWG_TOT), dim3(256), 0, stream>>>(p);
    }
}